// Round 4
// baseline (5841.489 us; speedup 1.0000x reference)
//
#include <hip/hip_runtime.h>
#include <math.h>

#define TT 64
#define BB 256
#define OBS 512
#define ACTN 16
#define EMB 512
#define HID 1024
#define NCAT 32
#define NCLS 32
#define ZD 1024
#define G3 3072
#define NBLK 512

typedef short s16x8 __attribute__((ext_vector_type(8)));
typedef float floatx4 __attribute__((ext_vector_type(4)));
typedef unsigned long long u64;

// barrier buffer layout (ints)
constexpr int CNT_OFF = 0;          // 8 census counters
constexpr int ARR_OFF = 16;         // 512*16 arrive slots
constexpr int REL_OFF = 16 + NBLK * 16;   // 8*16 per-XCD release lines
constexpr int BAR_INTS = REL_OFF + 8 * 16 + 16;

#define ALD(p)    __hip_atomic_load((p), __ATOMIC_RELAXED, __HIP_MEMORY_SCOPE_AGENT)
#define AST(p, v) __hip_atomic_store((p), (v), __ATOMIC_RELAXED, __HIP_MEMORY_SCOPE_AGENT)

__device__ __forceinline__ unsigned short f2bf(float f) {
    unsigned int u = __float_as_uint(f);
    unsigned int r = (u + 0x7fffu + ((u >> 16) & 1u)) >> 16;
    return (unsigned short)r;
}
__device__ __forceinline__ float bf2f(unsigned short h) {
    return __uint_as_float(((unsigned int)h) << 16);
}
__device__ __forceinline__ float elu1(float v) {
    return v > 0.f ? v : (expf(v) - 1.f);
}
__device__ __forceinline__ float sigm(float v) {
    return 1.f / (1.f + expf(-v));
}

// release: drain this wave's memory ops (incl. write-through AST stores)
__device__ __forceinline__ void rel_drain() {
    asm volatile("" ::: "memory");
    asm volatile("s_waitcnt vmcnt(0) lgkmcnt(0)" ::: "memory");
}
// acquire: invalidate vector L1 so fresh L2/L3 data is seen (does NOT flush L2)
__device__ __forceinline__ void acq_fence() {
    __builtin_amdgcn_fence(__ATOMIC_ACQUIRE, "agent");
    asm volatile("" ::: "memory");
}

// centralized global barrier, proven agent-atomic primitives only:
//   arrive: each block stores its slot (512 distinct lines)
//   detect: block 0's 256 threads poll 2 slots each
//   release: block 0 writes 8 per-XCD lines; each block's tid0 polls its line
__device__ __forceinline__ void gbar(int* bar, int grp, int ep) {
    rel_drain();
    __syncthreads();
    int tid = threadIdx.x;
    if (tid == 0)
        AST(&bar[ARR_OFF + blockIdx.x * 16], ep);
    if (blockIdx.x == 0) {
        for (int i = tid; i < NBLK; i += 256)
            while (ALD(&bar[ARR_OFF + i * 16]) < ep)
                __builtin_amdgcn_s_sleep(1);
        __syncthreads();
        if (tid < 8)
            AST(&bar[REL_OFF + tid * 16], ep);
    } else if (tid == 0) {
        while (ALD(&bar[REL_OFF + grp * 16]) < ep)
            __builtin_amdgcn_s_sleep(1);
    }
    __syncthreads();
    acq_fence();
}

// ---------------------------------------------------------------- one-hot -> index
__global__ void k_idx(const float* __restrict__ obs, const float* __restrict__ act,
                      int* __restrict__ obs_idx, int* __restrict__ act_idx) {
    int wave = (blockIdx.x * blockDim.x + threadIdx.x) >> 6;
    int lane = threadIdx.x & 63;
    if (wave >= TT * BB) return;
    const float* o = obs + (size_t)wave * OBS;
    int found = -1;
    #pragma unroll
    for (int j = 0; j < 8; ++j) {
        float v = o[lane + 64 * j];
        if (v > 0.5f) found = lane + 64 * j;
    }
    unsigned long long m = __ballot(found >= 0);
    int src = __ffsll(m) - 1;
    int oidx = __shfl(found, src);
    int af = -1;
    if (lane < ACTN) {
        float v = act[(size_t)wave * ACTN + lane];
        if (v > 0.5f) af = lane;
    }
    unsigned long long m2 = __ballot(af >= 0);
    int src2 = __ffsll(m2) - 1;
    int aidx = __shfl(af, src2);
    if (lane == 0) { obs_idx[wave] = oidx; act_idx[wave] = aidx; }
}

// ---------------------------------------------------------------- transpose fp32 -> bf16
__global__ void k_transp(const float* __restrict__ in, int instride,
                         unsigned short* __restrict__ out, int ldo, int ko) {
    __shared__ float t[32][33];
    int c0 = blockIdx.x * 32, r0 = blockIdx.y * 32;
    int tx = threadIdx.x, ty = threadIdx.y;
    #pragma unroll
    for (int i = 0; i < 4; ++i)
        t[ty + 8 * i][tx] = in[(size_t)(r0 + ty + 8 * i) * instride + c0 + tx];
    __syncthreads();
    #pragma unroll
    for (int i = 0; i < 4; ++i)
        out[(size_t)(c0 + ty + 8 * i) * ldo + ko + r0 + tx] = f2bf(t[tx][ty + 8 * i]);
}

__global__ void k_cast(const float* __restrict__ in, unsigned short* __restrict__ out, int n) {
    int i = blockIdx.x * 256 + threadIdx.x;
    if (i < n) out[i] = f2bf(in[i]);
}

__global__ void k_pack_bias(const float* bd1, const float* br1, const float* bc1,
                            float* __restrict__ out) {
    int i = threadIdx.x;
    if (i < 64) out[i] = bd1[i];
    else if (i < 128) out[i] = br1[i - 64];
    else out[i] = bc1[i - 128];
}

__global__ void k_e1(const int* __restrict__ obs_idx, const float* __restrict__ We1,
                     const float* __restrict__ be1, unsigned short* __restrict__ e1) {
    int g = blockIdx.x * 256 + threadIdx.x;
    int s = g >> 6, k = g & 63;
    float v = We1[obs_idx[s] * 64 + k] + be1[k];
    e1[g] = f2bf(elu1(v));
}

// ---------------------------------------------------------------- generic MFMA GEMM (batched)
struct MJob {
    const unsigned short* X; int ldx;
    const unsigned short* WT;
    const float* bias;
    const unsigned short* addb;
    void* out; int ldo;
    int N, K, flags;              // 1=elu, 2=bf16 out, 4=addb
};

__global__ __launch_bounds__(256) void mfma_gemm(MJob j) {
    __shared__ unsigned short Xs[64][40];
    __shared__ unsigned short Ns[64][40];
    int tid = threadIdx.x;
    int m0 = blockIdx.y * 64, n0 = blockIdx.x * 64;
    int r = tid >> 2, p = (tid & 3) * 8;
    const unsigned short* xg = j.X + (size_t)(m0 + r) * j.ldx + p;
    const unsigned short* wg = j.WT + (size_t)(n0 + r) * j.K + p;
    int lane = tid & 63, wv = tid >> 6;
    int wm = (wv & 1) * 32, wn = (wv >> 1) * 32;
    int mi = lane & 15, q = lane >> 4;
    floatx4 acc00 = {0.f, 0.f, 0.f, 0.f};
    floatx4 acc01 = acc00, acc10 = acc00, acc11 = acc00;
    for (int kt = 0; kt < j.K; kt += 32) {
        *(float4*)&Xs[r][p] = *(const float4*)(xg + kt);
        *(float4*)&Ns[r][p] = *(const float4*)(wg + kt);
        __syncthreads();
        s16x8 a0 = *(const s16x8*)&Xs[wm + mi][q * 8];
        s16x8 a1 = *(const s16x8*)&Xs[wm + 16 + mi][q * 8];
        s16x8 b0 = *(const s16x8*)&Ns[wn + mi][q * 8];
        s16x8 b1 = *(const s16x8*)&Ns[wn + 16 + mi][q * 8];
        acc00 = __builtin_amdgcn_mfma_f32_16x16x32_bf16(a0, b0, acc00, 0, 0, 0);
        acc01 = __builtin_amdgcn_mfma_f32_16x16x32_bf16(a0, b1, acc01, 0, 0, 0);
        acc10 = __builtin_amdgcn_mfma_f32_16x16x32_bf16(a1, b0, acc10, 0, 0, 0);
        acc11 = __builtin_amdgcn_mfma_f32_16x16x32_bf16(a1, b1, acc11, 0, 0, 0);
        __syncthreads();
    }
    #pragma unroll
    for (int i = 0; i < 2; ++i) {
        #pragma unroll
        for (int jj = 0; jj < 2; ++jj) {
            floatx4 a = (i == 0) ? ((jj == 0) ? acc00 : acc01)
                                 : ((jj == 0) ? acc10 : acc11);
            int col = n0 + wn + jj * 16 + mi;
            float badd = j.bias ? j.bias[col] : 0.f;
            #pragma unroll
            for (int rg = 0; rg < 4; ++rg) {
                int row = m0 + wm + i * 16 + q * 4 + rg;
                float v = a[rg] + badd;
                if (j.flags & 4) v += bf2f(j.addb[(size_t)row * j.N + col]);
                if (j.flags & 1) v = elu1(v);
                if (j.flags & 2)
                    ((unsigned short*)j.out)[(size_t)row * j.ldo + col] = f2bf(v);
                else
                    ((float*)j.out)[(size_t)row * j.ldo + col] = v;
            }
        }
    }
}

// ---------------------------------------------------------------- scan tile GEMM (64-col)
// C[32, 64] : A(LDS [32][1032], K=1024) @ WTb[64 rows][1024]^T
// wave wv (0..3) owns cols wv*16..+16. Per-lane B chain = 32 float4, prefetch depth 8.
__device__ __forceinline__ void gemm_tile16(const unsigned short (*As)[1032],
                                            const unsigned short* __restrict__ WTb,
                                            int lane, int wv, floatx4 acc[2]) {
    int mi = lane & 15, q = lane >> 4;
    const unsigned short* bg = WTb + (size_t)(wv * 16 + mi) * 1024 + q * 8;
    float4 pb[8];
    #pragma unroll
    for (int i = 0; i < 8; ++i) pb[i] = *(const float4*)(bg + i * 32);
    #pragma unroll
    for (int kk = 0; kk < 32; ++kk) {
        union { float4 f; s16x8 s; } b;
        b.f = pb[kk & 7];
        if (kk < 24) pb[kk & 7] = *(const float4*)(bg + (kk + 8) * 32);
        s16x8 a0 = *(const s16x8*)&As[mi][kk * 32 + q * 8];
        s16x8 a1 = *(const s16x8*)&As[16 + mi][kk * 32 + q * 8];
        acc[0] = __builtin_amdgcn_mfma_f32_16x16x32_bf16(a0, b.s, acc[0], 0, 0, 0);
        acc[1] = __builtin_amdgcn_mfma_f32_16x16x32_bf16(a1, b.s, acc[1], 0, 0, 0);
    }
}

__device__ __forceinline__ void loadA(unsigned short (*As)[1032],
                                      const unsigned short* __restrict__ src,
                                      int ldsrc, int tid) {
    #pragma unroll
    for (int i = 0; i < 16; ++i) {
        int e = (i * 256 + tid) * 8;
        int rowi = e >> 10, col = e & 1023;
        *(float4*)&As[rowi][col] = *(const float4*)(src + (size_t)rowi * ldsrc + col);
    }
}

// cache-bypassing (agent-scope) variant: for cross-XCD buffers with reused addresses
__device__ __forceinline__ void loadA_sc1(unsigned short (*As)[1032],
                                          const unsigned short* __restrict__ src,
                                          int ldsrc, int tid) {
    #pragma unroll
    for (int i = 0; i < 16; ++i) {
        int e = (i * 256 + tid) * 8;
        int rowi = e >> 10, col = e & 1023;
        const u64* sp = (const u64*)(src + (size_t)rowi * ldsrc + col);
        u64 a = ALD(sp);
        u64 b = ALD(sp + 1);
        *(u64*)&As[rowi][col] = a;
        *(u64*)&As[rowi][col + 4] = b;
    }
}

// ---------------------------------------------------------------- persistent col-split scan
// XCD-group cg owns h-column slice [cg*128, cg*128+128) for ALL 256 batch rows.
// Per-XCD L2-resident weights ~2MB < 4MB L2 (proven R2: FETCH 10x drop).
// NEW: 68KB LDS -> 2 independent blocks/CU (512 blocks) for latency overlap.
struct ScanP {
    const unsigned short *WhT, *Wq1aT, *Wq2T, *WizBF, *Eq;
    const float *Wi, *bi, *bh, *bq2, *gum;
    const int *act_idx;
    unsigned short *XZ, *post1c, *postL;
    float *ghbuf, *h_st;
    int *zidx;
    int *bar;
};

__global__ __launch_bounds__(256, 2) void k_scan(ScanP P) {
    __shared__ __align__(16) unsigned short As[32][1032];   // 66 KB -> 2 blocks/CU
    __shared__ int zsA[4][32];
    __shared__ int zact[4];
    __shared__ float scrW[256];
    __shared__ int sh_rank, sh_xcc, sh_cnt[8];
    int tid = threadIdx.x;
    int lane = tid & 63, wv = tid >> 6;
    int mi = lane & 15, q = lane >> 4;
    int* bar = P.bar;

    // ---- census: group = physical XCD
    if (tid == 0) {
        int xcc;
        asm volatile("s_getreg_b32 %0, hwreg(HW_REG_XCC_ID)" : "=s"(xcc));
        xcc &= 7;
        sh_xcc = xcc;
        sh_rank = atomicAdd(&bar[CNT_OFF + xcc], 1);
    }
    __syncthreads();
    int grp = sh_xcc, rank = sh_rank;

    // ---- entry barrier = epoch 1 of the unified barrier
    gbar(bar, grp, 1);

    if (tid < 8)
        sh_cnt[tid] = ALD(&bar[CNT_OFF + tid]);
    __syncthreads();
    int nb = sh_cnt[grp];
    int kg = 0, jg = 0;
    #pragma unroll
    for (int g = 0; g < 8; ++g) {
        if (sh_cnt[g] > 0) { if (g == grp) jg = kg; ++kg; }
    }
    int mych[8], nchunk = 0;
    for (int c = jg; c < 8; c += kg) mych[nchunk++] = c;

    int ep = 1;
    for (int t = 1; t <= TT; ++t) {
        // ---------- S_A: GRU; group owns h-cols [cg*128..+128), unit = 4 rows
        for (int ci = 0; ci < nchunk; ++ci) {
            int cg = mych[ci];
            int cb = cg * 128;
            for (int u = rank; u < 64; u += nb) {
                int r0 = u * 4;
                __syncthreads();
                if (tid < 128) {
                    int lr = tid >> 5, cc = tid & 31;
                    if (t > 1)
                        zsA[lr][cc] = cc * 32 +
                            ALD(&P.zidx[(r0 + lr) * 32 + cc]);   // fresh cross-XCD
                }
                if (tid < 4)
                    zact[tid] = 1024 + P.act_idx[(t - 1) * 256 + r0 + tid];
                __syncthreads();
                int rr = tid >> 6, ln = tid & 63;
                int grow = r0 + rr;
                int j0 = cb + ln * 2;
                float g0v[2] = {0.f, 0.f};
                float g1v[2] = {0.f, 0.f};
                float g2v[2] = {0.f, 0.f};
                if (t > 1) {
                    #pragma unroll 4
                    for (int cc = 0; cc < 32; ++cc) {
                        const unsigned short* wr =
                            P.WizBF + (size_t)zsA[rr][cc] * G3 + j0;
                        unsigned int w0 = *(const unsigned int*)wr;
                        unsigned int w1 = *(const unsigned int*)(wr + 1024);
                        unsigned int w2 = *(const unsigned int*)(wr + 2048);
                        g0v[0] += bf2f((unsigned short)w0);
                        g0v[1] += bf2f((unsigned short)(w0 >> 16));
                        g1v[0] += bf2f((unsigned short)w1);
                        g1v[1] += bf2f((unsigned short)(w1 >> 16));
                        g2v[0] += bf2f((unsigned short)w2);
                        g2v[1] += bf2f((unsigned short)(w2 >> 16));
                    }
                }
                const float* wa = P.Wi + (size_t)zact[rr] * G3;
                float2 bi0 = *(const float2*)(P.bi + j0);
                float2 bi1 = *(const float2*)(P.bi + 1024 + j0);
                float2 bi2 = *(const float2*)(P.bi + 2048 + j0);
                float2 wa0 = *(const float2*)(wa + j0);
                float2 wa1 = *(const float2*)(wa + 1024 + j0);
                float2 wa2 = *(const float2*)(wa + 2048 + j0);
                g0v[0] += bi0.x + wa0.x; g0v[1] += bi0.y + wa0.y;
                g1v[0] += bi1.x + wa1.x; g1v[1] += bi1.y + wa1.y;
                g2v[0] += bi2.x + wa2.x; g2v[1] += bi2.y + wa2.y;
                const float* ghs = (t == 1) ? P.bh : (P.ghbuf + (size_t)grow * G3);
                float2 gr2 = *(const float2*)(ghs + j0);
                float2 gu2 = *(const float2*)(ghs + 1024 + j0);
                float2 gn2 = *(const float2*)(ghs + 2048 + j0);
                float2 hp2 = *(const float2*)(P.h_st + (size_t)grow * HID + j0);
                float grv[2] = {gr2.x, gr2.y};
                float guv[2] = {gu2.x, gu2.y};
                float gnv[2] = {gn2.x, gn2.y};
                float hpv[2] = {hp2.x, hp2.y};
                float ho[2];
                #pragma unroll
                for (int kq = 0; kq < 2; ++kq) {
                    float rr2 = sigm(g0v[kq] + grv[kq]);
                    float uu = sigm(g1v[kq] + guv[kq]);
                    float nn = tanhf(g2v[kq] + rr2 * gnv[kq]);
                    ho[kq] = (1.f - uu) * nn + uu * hpv[kq];
                }
                *(float2*)(P.h_st + (size_t)grow * HID + j0) = make_float2(ho[0], ho[1]);
                unsigned int pk = (unsigned int)f2bf(ho[0]) |
                                  ((unsigned int)f2bf(ho[1]) << 16);
                // cross-XCD consumer (S_B loadA): write-through to L3
                AST((unsigned int*)(P.XZ + ((size_t)t * 256 + grow) * 2048 + j0), pk);
            }
        }
        gbar(bar, grp, ++ep);

        // ---------- S_B: unit = (jobsel 0..3, chunk 0..7, half 0..1); 64 units
        for (int ci = 0; ci < nchunk; ++ci) {
            int cg = mych[ci];
            for (int u = rank; u < 64; u += nb) {
                int jobsel = u >> 4, rem = u & 15;
                int c = rem >> 1, half = rem & 1;
                if (jobsel < 3 && t == TT) continue;
                __syncthreads();
                loadA(As, P.XZ + ((size_t)t * 256 + c * 32) * 2048, 2048, tid);
                __syncthreads();
                if (jobsel < 3) {
                    int jj = jobsel * 8 + cg;
                    int base_n = jj * 128 + half * 64;
                    floatx4 z4 = {0.f, 0.f, 0.f, 0.f};
                    floatx4 acc[2] = {z4, z4};
                    gemm_tile16(As, P.WhT + (size_t)base_n * 1024, lane, wv, acc);
                    int col = base_n + wv * 16 + mi;
                    float bb = P.bh[col];
                    #pragma unroll
                    for (int mt = 0; mt < 2; ++mt)
                        #pragma unroll
                        for (int rg = 0; rg < 4; ++rg) {
                            int grow = c * 32 + mt * 16 + q * 4 + rg;
                            P.ghbuf[(size_t)grow * G3 + col] = acc[mt][rg] + bb;
                        }
                } else {
                    int base_n = cg * 128 + half * 64;
                    int col = base_n + wv * 16 + mi;
                    // prefetch Eq adds before GEMM (latency hides under MFMA)
                    unsigned short pe[2][4];
                    #pragma unroll
                    for (int mt = 0; mt < 2; ++mt)
                        #pragma unroll
                        for (int rg = 0; rg < 4; ++rg) {
                            int grow = c * 32 + mt * 16 + q * 4 + rg;
                            pe[mt][rg] = __builtin_nontemporal_load(
                                P.Eq + ((size_t)(t - 1) * 256 + grow) * 1024 + col);
                        }
                    floatx4 z4 = {0.f, 0.f, 0.f, 0.f};
                    floatx4 acc[2] = {z4, z4};
                    gemm_tile16(As, P.Wq1aT + (size_t)base_n * 1024, lane, wv, acc);
                    #pragma unroll
                    for (int mt = 0; mt < 2; ++mt)
                        #pragma unroll
                        for (int rg = 0; rg < 4; ++rg) {
                            int lr = mt * 16 + q * 4 + rg;
                            float v = elu1(acc[mt][rg] + bf2f(pe[mt][rg]));
                            // cross-XCD consumer (S_C): write-through
                            AST(&P.post1c[(size_t)c * 32768 + lr * 1024 + col], f2bf(v));
                        }
                }
            }
        }
        gbar(bar, grp, ++ep);

        // ---------- S_C: unit = (chunk 0..7, half 0..1); 16 units
        for (int ci = 0; ci < nchunk; ++ci) {
            int cg = mych[ci];
            for (int u = rank; u < 16; u += nb) {
                int c = u >> 1, half = u & 1;
                __syncthreads();
                loadA_sc1(As, P.post1c + (size_t)c * 32768, 1024, tid);
                __syncthreads();
                int base_n = cg * 128 + half * 64;
                int cat = cg * 4 + half * 2 + (wv >> 1);
                int half16 = wv & 1;
                // prefetch gumbel before GEMM
                float pg[2][4];
                #pragma unroll
                for (int mt = 0; mt < 2; ++mt)
                    #pragma unroll
                    for (int rg = 0; rg < 4; ++rg) {
                        int grow = c * 32 + mt * 16 + q * 4 + rg;
                        pg[mt][rg] = __builtin_nontemporal_load(
                            P.gum + ((size_t)(t - 1) * 256 + grow) * 1024 +
                            cat * 32 + half16 * 16 + mi);
                    }
                floatx4 z4 = {0.f, 0.f, 0.f, 0.f};
                floatx4 acc[2] = {z4, z4};
                gemm_tile16(As, P.Wq2T + (size_t)base_n * 1024, lane, wv, acc);
                int col = base_n + wv * 16 + mi;
                float bb = P.bq2[col];
                #pragma unroll
                for (int mt = 0; mt < 2; ++mt)
                    #pragma unroll
                    for (int rg = 0; rg < 4; ++rg) {
                        acc[mt][rg] += bb;
                        int grow = c * 32 + mt * 16 + q * 4 + rg;
                        __builtin_nontemporal_store(f2bf(acc[mt][rg]),
                            P.postL + ((size_t)(t - 1) * 256 + grow) * 1024 + col);
                    }
                // local argmax over this wave's 16 cols (half-category)
                float fbv[2][4]; int fcl[2][4];
                #pragma unroll
                for (int mt = 0; mt < 2; ++mt) {
                    #pragma unroll
                    for (int rg = 0; rg < 4; ++rg) {
                        float bv = acc[mt][rg] + pg[mt][rg];
                        int cls = half16 * 16 + mi;
                        #pragma unroll
                        for (int off = 1; off < 16; off <<= 1) {
                            float ov = __shfl_xor(bv, off);
                            int oc = __shfl_xor(cls, off);
                            if (ov > bv || (ov == bv && oc < cls)) { bv = ov; cls = oc; }
                        }
                        fbv[mt][rg] = bv; fcl[mt][rg] = cls;
                        if (mi == 0) {
                            float2* w = (float2*)&scrW[((wv * 4 + q) * 8 + mt * 4 + rg) * 2];
                            *w = make_float2(bv, __int_as_float(cls));
                        }
                    }
                }
                __syncthreads();
                int pw = wv ^ 1;
                #pragma unroll
                for (int mt = 0; mt < 2; ++mt) {
                    #pragma unroll
                    for (int rg = 0; rg < 4; ++rg) {
                        float2 o = *(const float2*)&scrW[((pw * 4 + q) * 8 + mt * 4 + rg) * 2];
                        float bv = fbv[mt][rg]; int cls = fcl[mt][rg];
                        int oc = __float_as_int(o.y);
                        if (o.x > bv || (o.x == bv && oc < cls)) { bv = o.x; cls = oc; }
                        int grow = c * 32 + mt * 16 + q * 4 + rg;
                        unsigned short* zo =
                            P.XZ + ((size_t)t * 256 + grow) * 2048 + 1024 + cat * 32;
                        zo[half16 * 16 + mi] = (half16 * 16 + mi == cls) ? 0x3F80 : 0;
                        if (half16 == 0 && mi == 0)
                            AST(&P.zidx[grow * 32 + cat], cls);   // cross-XCD (next S_A)
                    }
                }
            }
        }
        gbar(bar, grp, ++ep);
    }
}

// ---------------------------------------------------------------- KL (deferred)
__global__ void k_kl(const unsigned short* __restrict__ postL,
                     const unsigned short* __restrict__ priorL,
                     float* __restrict__ kl_acc) {
    int g = blockIdx.x * 256 + threadIdx.x;
    int sidx = g >> 5, cat = g & 31;
    const unsigned short* ql = postL + (size_t)sidx * ZD + cat * NCLS;
    const unsigned short* pl = priorL + (size_t)sidx * ZD + cat * NCLS;
    float vq[32], vp[32];
    float mq = -1e30f, mp = -1e30f;
    #pragma unroll
    for (int i = 0; i < NCLS; ++i) {
        vq[i] = bf2f(ql[i]); vp[i] = bf2f(pl[i]);
        mq = fmaxf(mq, vq[i]); mp = fmaxf(mp, vp[i]);
    }
    float sq = 0.f, sp = 0.f;
    #pragma unroll
    for (int i = 0; i < NCLS; ++i) { sq += expf(vq[i] - mq); sp += expf(vp[i] - mp); }
    float lseq = mq + logf(sq), lsep = mp + logf(sp);
    float kl = 0.f;
    #pragma unroll
    for (int i = 0; i < NCLS; ++i) {
        float lpq = vq[i] - lseq;
        kl += expf(lpq) * (lpq - (vp[i] - lsep));
    }
    __shared__ float red[256];
    red[threadIdx.x] = kl;
    __syncthreads();
    for (int s = 128; s > 0; s >>= 1) {
        if ((int)threadIdx.x < s) red[threadIdx.x] += red[threadIdx.x + s];
        __syncthreads();
    }
    if (threadIdx.x == 0) atomicAdd(&kl_acc[sidx >> 8], red[0]);
}

// ---------------------------------------------------------------- CE over 512 logits
__global__ void k_ce(const unsigned short* __restrict__ logits,
                     const int* __restrict__ obs_idx, float* __restrict__ ce_acc) {
    int s = (blockIdx.x * 256 + threadIdx.x) >> 6;
    int lane = threadIdx.x & 63;
    union { float4 f4; unsigned short u[8]; } raw;
    raw.f4 = *(const float4*)(logits + (size_t)s * OBS + lane * 8);
    float v[8];
    float m = -1e30f;
    #pragma unroll
    for (int i = 0; i < 8; ++i) { v[i] = bf2f(raw.u[i]); m = fmaxf(m, v[i]); }
    #pragma unroll
    for (int off = 32; off > 0; off >>= 1) m = fmaxf(m, __shfl_xor(m, off));
    float sum = 0.f;
    #pragma unroll
    for (int i = 0; i < 8; ++i) sum += expf(v[i] - m);
    #pragma unroll
    for (int off = 32; off > 0; off >>= 1) sum += __shfl_xor(sum, off);
    float lse = m + logf(sum);
    int tgt = obs_idx[s];
    float tv = 0.f;
    #pragma unroll
    for (int i = 0; i < 8; ++i) if (lane * 8 + i == tgt) tv = v[i];
    #pragma unroll
    for (int off = 32; off > 0; off >>= 1) tv += __shfl_xor(tv, off);
    if (lane == 0) atomicAdd(&ce_acc[s >> 8], lse - tv);
}

// ---------------------------------------------------------------- reward / continue heads
__global__ void k_heads(const unsigned short* __restrict__ dec1,
                        const float* __restrict__ Wr2, const float* __restrict__ br2,
                        const float* __restrict__ Wc2, const float* __restrict__ bc2,
                        const float* __restrict__ rew, const float* __restrict__ done,
                        float* __restrict__ mse_acc, float* __restrict__ bce_acc) {
    int s = (blockIdx.x * 256 + threadIdx.x) >> 6;
    int lane = threadIdx.x & 63;
    float vr = bf2f(dec1[(size_t)s * 192 + 64 + lane]) * Wr2[lane];
    float vc = bf2f(dec1[(size_t)s * 192 + 128 + lane]) * Wc2[lane];
    #pragma unroll
    for (int off = 32; off > 0; off >>= 1) {
        vr += __shfl_xor(vr, off);
        vc += __shfl_xor(vc, off);
    }
    if (lane == 0) {
        float r_pred = vr + br2[0], c_pred = vc + bc2[0];
        float rt = rew[s];
        float sgn = (rt > 0.f) ? 1.f : ((rt < 0.f) ? -1.f : 0.f);
        float r_tgt = sgn * log1pf(fabsf(rt));
        float d = r_pred - r_tgt;
        float ct = 1.f - done[s];
        float bce = fmaxf(c_pred, 0.f) - c_pred * ct + log1pf(expf(-fabsf(c_pred)));
        atomicAdd(&mse_acc[s >> 8], d * d);
        atomicAdd(&bce_acc[s >> 8], bce);
    }
}

// ---------------------------------------------------------------- final reduce
__global__ void k_final(const float* __restrict__ ce_acc, const float* __restrict__ mse_acc,
                        const float* __restrict__ bce_acc, const float* __restrict__ kl_acc,
                        float* __restrict__ out) {
    int t = threadIdx.x;
    float ce = ce_acc[t] * (1.f / 256.f);
    float ms = mse_acc[t] * (1.f / 256.f);
    float bc = bce_acc[t] * (1.f / 256.f);
    float ka = kl_acc[t] * (1.f / 256.f);
    float kt = fmaxf(ka, 1.f);
    #pragma unroll
    for (int off = 32; off > 0; off >>= 1) {
        ce += __shfl_down(ce, off);
        ms += __shfl_down(ms, off);
        bc += __shfl_down(bc, off);
        kt += __shfl_down(kt, off);
    }
    if (t == 0) {
        ce *= (1.f / 64.f); ms *= (1.f / 64.f); bc *= (1.f / 64.f); kt *= (1.f / 64.f);
        out[0] = ce + ms + bc + kt;
        out[1] = ce; out[2] = ms; out[3] = bc; out[4] = kt;
    }
}

// ----------------------------------------------------------------------------------
extern "C" void kernel_launch(void* const* d_in, const int* in_sizes, int n_in,
                              void* d_out, int out_size, void* d_ws, size_t ws_size,
                              hipStream_t stream) {
    const float* obs  = (const float*)d_in[0];
    const float* act  = (const float*)d_in[1];
    const float* rew  = (const float*)d_in[2];
    const float* done = (const float*)d_in[3];
    const float* gum  = (const float*)d_in[4];
    const float* We1  = (const float*)d_in[5];
    const float* be1  = (const float*)d_in[6];
    const float* We2  = (const float*)d_in[7];
    const float* be2  = (const float*)d_in[8];
    const float* Wi   = (const float*)d_in[9];
    const float* Wh   = (const float*)d_in[10];
    const float* bi   = (const float*)d_in[11];
    const float* bh   = (const float*)d_in[12];
    const float* Wp1  = (const float*)d_in[13];
    const float* bp1  = (const float*)d_in[14];
    const float* Wp2  = (const float*)d_in[15];
    const float* bp2  = (const float*)d_in[16];
    const float* Wq1  = (const float*)d_in[17];
    const float* bq1  = (const float*)d_in[18];
    const float* Wq2  = (const float*)d_in[19];
    const float* bq2  = (const float*)d_in[20];
    const float* Wd1  = (const float*)d_in[21];
    const float* bd1  = (const float*)d_in[22];
    const float* Wd2  = (const float*)d_in[23];
    const float* bd2  = (const float*)d_in[24];
    const float* Wr1  = (const float*)d_in[25];
    const float* br1  = (const float*)d_in[26];
    const float* Wr2  = (const float*)d_in[27];
    const float* br2  = (const float*)d_in[28];
    const float* Wc1  = (const float*)d_in[29];
    const float* bc1  = (const float*)d_in[30];
    const float* Wc2  = (const float*)d_in[31];
    const float* bc2  = (const float*)d_in[32];

    char* base = (char*)d_ws;
    size_t off = 0;
    auto alloc = [&](size_t bytes) -> char* {
        char* p = base + off;
        off += (bytes + 255) & ~(size_t)255;
        return p;
    };
    unsigned short* WhT   = (unsigned short*)alloc(3072u * 1024 * 2);
    unsigned short* WizBF = (unsigned short*)alloc(1024u * 3072 * 2);
    unsigned short* Wq1aT = (unsigned short*)alloc(1024u * 1024 * 2);
    unsigned short* Wq1bT = (unsigned short*)alloc(1024u * 512 * 2);
    unsigned short* Wq2T  = (unsigned short*)alloc(1024u * 1024 * 2);
    unsigned short* Wp1T  = (unsigned short*)alloc(1024u * 1024 * 2);
    unsigned short* Wp2T  = (unsigned short*)alloc(1024u * 1024 * 2);
    unsigned short* WdrcT = (unsigned short*)alloc(192u * 2048 * 2);
    unsigned short* Wd2T  = (unsigned short*)alloc(512u * 64 * 2);
    unsigned short* We2T  = (unsigned short*)alloc(512u * 64 * 2);
    float*          b_drc = (float*)alloc(192 * 4);
    unsigned short* XZ    = (unsigned short*)alloc(65u * 256 * 2048 * 2);   // 68 MB
    float*          h_st  = (float*)alloc(256u * 1024 * 4);
    float*          ghbuf = (float*)alloc(256u * 3072 * 4);
    unsigned short* post1c= (unsigned short*)alloc(8u * 32 * 1024 * 2);
    unsigned short* postL = (unsigned short*)alloc(16384u * 1024 * 2);      // 32 MB (reused: logits)
    unsigned short* Eq    = (unsigned short*)alloc(16384u * 1024 * 2);      // 32 MB (reused: priorL)
    unsigned short* pri1  = (unsigned short*)alloc(16384u * 1024 * 2);      // 32 MB
    unsigned short* dec1  = (unsigned short*)alloc(16384u * 192 * 2);
    float*          acc   = (float*)alloc(256 * 4);
    int*            obs_idx = (int*)alloc(16384 * 4);
    int*            act_idx = (int*)alloc(16384 * 4);
    int*            zidx    = (int*)alloc(256 * 32 * 4);
    int*            bar     = (int*)alloc(BAR_INTS * 4);
    unsigned short* embed = pri1;                    // setup-time aliases (pri1 unused then)
    unsigned short* e1    = pri1 + 16384u * 512;

    hipMemsetAsync(h_st, 0, 256u * 1024 * 4, stream);
    hipMemsetAsync(acc, 0, 256 * 4, stream);
    hipMemsetAsync(bar, 0, BAR_INTS * 4, stream);

    k_idx<<<4096, 256, 0, stream>>>(obs, act, obs_idx, act_idx);

    dim3 tb(32, 8);
    k_transp<<<dim3(96, 32), tb, 0, stream>>>(Wh, 3072, WhT, 1024, 0);
    k_cast<<<(1024 * 3072) / 256, 256, 0, stream>>>(Wi, WizBF, 1024 * 3072);
    k_transp<<<dim3(32, 32), tb, 0, stream>>>(Wq1, 1024, Wq1aT, 1024, 0);
    k_transp<<<dim3(32, 16), tb, 0, stream>>>(Wq1 + 1024u * 1024, 1024, Wq1bT, 512, 0);
    k_transp<<<dim3(32, 32), tb, 0, stream>>>(Wq2, 1024, Wq2T, 1024, 0);
    k_transp<<<dim3(32, 32), tb, 0, stream>>>(Wp1, 1024, Wp1T, 1024, 0);
    k_transp<<<dim3(32, 32), tb, 0, stream>>>(Wp2, 1024, Wp2T, 1024, 0);
    k_transp<<<dim3(2, 64),  tb, 0, stream>>>(Wd1, 64, WdrcT, 2048, 0);
    k_transp<<<dim3(2, 64),  tb, 0, stream>>>(Wr1, 64, WdrcT + 64u * 2048, 2048, 0);
    k_transp<<<dim3(2, 64),  tb, 0, stream>>>(Wc1, 64, WdrcT + 128u * 2048, 2048, 0);
    k_transp<<<dim3(16, 2),  tb, 0, stream>>>(Wd2, 512, Wd2T, 64, 0);
    k_transp<<<dim3(16, 2),  tb, 0, stream>>>(We2, 512, We2T, 64, 0);
    k_pack_bias<<<1, 192, 0, stream>>>(bd1, br1, bc1, b_drc);

    // embed & Eq precompute (all 64 steps)
    k_e1<<<4096, 256, 0, stream>>>(obs_idx, We1, be1, e1);
    {
        MJob m = { e1, 64, We2T, be2, nullptr, embed, 512, 512, 64, 2 };
        mfma_gemm<<<dim3(8, 256), 256, 0, stream>>>(m);
    }
    {
        MJob m = { embed, 512, Wq1bT, bq1, nullptr, Eq, 1024, 1024, 512, 2 };
        mfma_gemm<<<dim3(16, 256), 256, 0, stream>>>(m);
    }

    // persistent col-split scan (cooperative launch for co-residency; 2 blocks/CU)
    ScanP SP;
    SP.WhT = WhT; SP.Wq1aT = Wq1aT; SP.Wq2T = Wq2T; SP.WizBF = WizBF; SP.Eq = Eq;
    SP.Wi = Wi; SP.bi = bi; SP.bh = bh; SP.bq2 = bq2; SP.gum = gum;
    SP.act_idx = act_idx;
    SP.XZ = XZ; SP.post1c = post1c; SP.postL = postL;
    SP.ghbuf = ghbuf; SP.h_st = h_st; SP.zidx = zidx; SP.bar = bar;
    void* kargs[] = { (void*)&SP };
    hipLaunchCooperativeKernel((const void*)k_scan, dim3(NBLK), dim3(256), kargs, 0, stream);

    // deferred batched passes
    unsigned short* Hall = XZ + (size_t)256 * 2048;
    {   // prior1 = elu(H @ Wp1 + bp1)
        MJob m = { Hall, 2048, Wp1T, bp1, nullptr, pri1, 1024, 1024, 1024, 1 | 2 };
        mfma_gemm<<<dim3(16, 256), 256, 0, stream>>>(m);
    }
    {   // priorL = prior1 @ Wp2 + bp2 (into Eq buffer)
        MJob m = { pri1, 1024, Wp2T, bp2, nullptr, Eq, 1024, 1024, 1024, 2 };
        mfma_gemm<<<dim3(16, 256), 256, 0, stream>>>(m);
    }
    k_kl<<<2048, 256, 0, stream>>>(postL, Eq, acc + 192);
    {
        MJob m = { Hall, 2048, WdrcT, b_drc, nullptr, dec1, 192, 192, 2048, 1 | 2 };
        mfma_gemm<<<dim3(3, 256), 256, 0, stream>>>(m);
    }
    {
        MJob m = { dec1, 192, Wd2T, bd2, nullptr, postL, 512, 512, 64, 2 };
        mfma_gemm<<<dim3(8, 256), 256, 0, stream>>>(m);
    }
    k_ce<<<4096, 256, 0, stream>>>(postL, obs_idx, acc + 0);
    k_heads<<<4096, 256, 0, stream>>>(dec1, Wr2, br2, Wc2, bc2, rew, done,
                                      acc + 64, acc + 128);
    k_final<<<1, 64, 0, stream>>>(acc + 0, acc + 64, acc + 128, acc + 192, (float*)d_out);
}

// Round 5
// 5819.378 us; speedup vs baseline: 1.0038x; 1.0038x over previous
//
#include <hip/hip_runtime.h>
#include <math.h>

#define TT 64
#define BB 256
#define OBS 512
#define ACTN 16
#define EMB 512
#define HID 1024
#define NCAT 32
#define NCLS 32
#define ZD 1024
#define G3 3072
#define NBLK 512
#define SLOTP 262144          // post1cT u16 per step slot (8*32*1024)
#define SLOTZ 8192            // zidxT ints per step slot (256*32)

typedef short s16x8 __attribute__((ext_vector_type(8)));
typedef float floatx4 __attribute__((ext_vector_type(4)));
typedef unsigned long long u64;

// barrier buffer layout (ints)
constexpr int CNT_OFF = 0;          // 8 census counters
constexpr int ARR_OFF = 16;         // 512*16 arrive slots
constexpr int REL_OFF = 16 + NBLK * 16;   // 8*16 per-XCD release lines
constexpr int BAR_INTS = REL_OFF + 8 * 16 + 16;

#define ALD(p)    __hip_atomic_load((p), __ATOMIC_RELAXED, __HIP_MEMORY_SCOPE_AGENT)
#define AST(p, v) __hip_atomic_store((p), (v), __ATOMIC_RELAXED, __HIP_MEMORY_SCOPE_AGENT)

__device__ __forceinline__ unsigned short f2bf(float f) {
    unsigned int u = __float_as_uint(f);
    unsigned int r = (u + 0x7fffu + ((u >> 16) & 1u)) >> 16;
    return (unsigned short)r;
}
__device__ __forceinline__ float bf2f(unsigned short h) {
    return __uint_as_float(((unsigned int)h) << 16);
}
__device__ __forceinline__ float elu1(float v) {
    return v > 0.f ? v : (expf(v) - 1.f);
}
__device__ __forceinline__ float sigm(float v) {
    return 1.f / (1.f + expf(-v));
}

// release: drain this wave's memory ops (incl. write-through AST stores)
__device__ __forceinline__ void rel_drain() {
    asm volatile("" ::: "memory");
    asm volatile("s_waitcnt vmcnt(0) lgkmcnt(0)" ::: "memory");
}
// acquire: invalidate vector L1 so fresh L2/L3 data is seen (does NOT flush L2)
__device__ __forceinline__ void acq_fence() {
    __builtin_amdgcn_fence(__ATOMIC_ACQUIRE, "agent");
    asm volatile("" ::: "memory");
}

// centralized global barrier, proven agent-atomic primitives only:
//   arrive: each block stores its slot (512 distinct lines)
//   detect: block 0's 256 threads poll 2 slots each
//   release: block 0 writes 8 per-XCD lines; each block's tid0 polls its line
__device__ __forceinline__ void gbar(int* bar, int grp, int ep) {
    rel_drain();
    __syncthreads();
    int tid = threadIdx.x;
    if (tid == 0)
        AST(&bar[ARR_OFF + blockIdx.x * 16], ep);
    if (blockIdx.x == 0) {
        for (int i = tid; i < NBLK; i += 256)
            while (ALD(&bar[ARR_OFF + i * 16]) < ep)
                __builtin_amdgcn_s_sleep(1);
        __syncthreads();
        if (tid < 8)
            AST(&bar[REL_OFF + tid * 16], ep);
    } else if (tid == 0) {
        while (ALD(&bar[REL_OFF + grp * 16]) < ep)
            __builtin_amdgcn_s_sleep(1);
    }
    __syncthreads();
    acq_fence();
}

// ---------------------------------------------------------------- one-hot -> index
__global__ void k_idx(const float* __restrict__ obs, const float* __restrict__ act,
                      int* __restrict__ obs_idx, int* __restrict__ act_idx) {
    int wave = (blockIdx.x * blockDim.x + threadIdx.x) >> 6;
    int lane = threadIdx.x & 63;
    if (wave >= TT * BB) return;
    const float* o = obs + (size_t)wave * OBS;
    int found = -1;
    #pragma unroll
    for (int j = 0; j < 8; ++j) {
        float v = o[lane + 64 * j];
        if (v > 0.5f) found = lane + 64 * j;
    }
    unsigned long long m = __ballot(found >= 0);
    int src = __ffsll(m) - 1;
    int oidx = __shfl(found, src);
    int af = -1;
    if (lane < ACTN) {
        float v = act[(size_t)wave * ACTN + lane];
        if (v > 0.5f) af = lane;
    }
    unsigned long long m2 = __ballot(af >= 0);
    int src2 = __ffsll(m2) - 1;
    int aidx = __shfl(af, src2);
    if (lane == 0) { obs_idx[wave] = oidx; act_idx[wave] = aidx; }
}

// ---------------------------------------------------------------- transpose fp32 -> bf16
__global__ void k_transp(const float* __restrict__ in, int instride,
                         unsigned short* __restrict__ out, int ldo, int ko) {
    __shared__ float t[32][33];
    int c0 = blockIdx.x * 32, r0 = blockIdx.y * 32;
    int tx = threadIdx.x, ty = threadIdx.y;
    #pragma unroll
    for (int i = 0; i < 4; ++i)
        t[ty + 8 * i][tx] = in[(size_t)(r0 + ty + 8 * i) * instride + c0 + tx];
    __syncthreads();
    #pragma unroll
    for (int i = 0; i < 4; ++i)
        out[(size_t)(c0 + ty + 8 * i) * ldo + ko + r0 + tx] = f2bf(t[tx][ty + 8 * i]);
}

__global__ void k_cast(const float* __restrict__ in, unsigned short* __restrict__ out, int n) {
    int i = blockIdx.x * 256 + threadIdx.x;
    if (i < n) out[i] = f2bf(in[i]);
}

__global__ void k_pack_bias(const float* bd1, const float* br1, const float* bc1,
                            float* __restrict__ out) {
    int i = threadIdx.x;
    if (i < 64) out[i] = bd1[i];
    else if (i < 128) out[i] = br1[i - 64];
    else out[i] = bc1[i - 128];
}

__global__ void k_e1(const int* __restrict__ obs_idx, const float* __restrict__ We1,
                     const float* __restrict__ be1, unsigned short* __restrict__ e1) {
    int g = blockIdx.x * 256 + threadIdx.x;
    int s = g >> 6, k = g & 63;
    float v = We1[obs_idx[s] * 64 + k] + be1[k];
    e1[g] = f2bf(elu1(v));
}

// ---------------------------------------------------------------- generic MFMA GEMM (batched)
struct MJob {
    const unsigned short* X; int ldx;
    const unsigned short* WT;
    const float* bias;
    const unsigned short* addb;
    void* out; int ldo;
    int N, K, flags;              // 1=elu, 2=bf16 out, 4=addb
};

__global__ __launch_bounds__(256) void mfma_gemm(MJob j) {
    __shared__ unsigned short Xs[64][40];
    __shared__ unsigned short Ns[64][40];
    int tid = threadIdx.x;
    int m0 = blockIdx.y * 64, n0 = blockIdx.x * 64;
    int r = tid >> 2, p = (tid & 3) * 8;
    const unsigned short* xg = j.X + (size_t)(m0 + r) * j.ldx + p;
    const unsigned short* wg = j.WT + (size_t)(n0 + r) * j.K + p;
    int lane = tid & 63, wv = tid >> 6;
    int wm = (wv & 1) * 32, wn = (wv >> 1) * 32;
    int mi = lane & 15, q = lane >> 4;
    floatx4 acc00 = {0.f, 0.f, 0.f, 0.f};
    floatx4 acc01 = acc00, acc10 = acc00, acc11 = acc00;
    for (int kt = 0; kt < j.K; kt += 32) {
        *(float4*)&Xs[r][p] = *(const float4*)(xg + kt);
        *(float4*)&Ns[r][p] = *(const float4*)(wg + kt);
        __syncthreads();
        s16x8 a0 = *(const s16x8*)&Xs[wm + mi][q * 8];
        s16x8 a1 = *(const s16x8*)&Xs[wm + 16 + mi][q * 8];
        s16x8 b0 = *(const s16x8*)&Ns[wn + mi][q * 8];
        s16x8 b1 = *(const s16x8*)&Ns[wn + 16 + mi][q * 8];
        acc00 = __builtin_amdgcn_mfma_f32_16x16x32_bf16(a0, b0, acc00, 0, 0, 0);
        acc01 = __builtin_amdgcn_mfma_f32_16x16x32_bf16(a0, b1, acc01, 0, 0, 0);
        acc10 = __builtin_amdgcn_mfma_f32_16x16x32_bf16(a1, b0, acc10, 0, 0, 0);
        acc11 = __builtin_amdgcn_mfma_f32_16x16x32_bf16(a1, b1, acc11, 0, 0, 0);
        __syncthreads();
    }
    #pragma unroll
    for (int i = 0; i < 2; ++i) {
        #pragma unroll
        for (int jj = 0; jj < 2; ++jj) {
            floatx4 a = (i == 0) ? ((jj == 0) ? acc00 : acc01)
                                 : ((jj == 0) ? acc10 : acc11);
            int col = n0 + wn + jj * 16 + mi;
            float badd = j.bias ? j.bias[col] : 0.f;
            #pragma unroll
            for (int rg = 0; rg < 4; ++rg) {
                int row = m0 + wm + i * 16 + q * 4 + rg;
                float v = a[rg] + badd;
                if (j.flags & 4) v += bf2f(j.addb[(size_t)row * j.N + col]);
                if (j.flags & 1) v = elu1(v);
                if (j.flags & 2)
                    ((unsigned short*)j.out)[(size_t)row * j.ldo + col] = f2bf(v);
                else
                    ((float*)j.out)[(size_t)row * j.ldo + col] = v;
            }
        }
    }
}

// ---------------------------------------------------------------- scan tile GEMM (64-col)
// C[32, 64] : A(LDS [32][1032], K=1024) @ WTb[64 rows][1024]^T
// wave wv (0..3) owns cols wv*16..+16. Per-lane B chain = 32 float4, prefetch depth 8.
__device__ __forceinline__ void gemm_tile16(const unsigned short (*As)[1032],
                                            const unsigned short* __restrict__ WTb,
                                            int lane, int wv, floatx4 acc[2]) {
    int mi = lane & 15, q = lane >> 4;
    const unsigned short* bg = WTb + (size_t)(wv * 16 + mi) * 1024 + q * 8;
    float4 pb[8];
    #pragma unroll
    for (int i = 0; i < 8; ++i) pb[i] = *(const float4*)(bg + i * 32);
    #pragma unroll
    for (int kk = 0; kk < 32; ++kk) {
        union { float4 f; s16x8 s; } b;
        b.f = pb[kk & 7];
        if (kk < 24) pb[kk & 7] = *(const float4*)(bg + (kk + 8) * 32);
        s16x8 a0 = *(const s16x8*)&As[mi][kk * 32 + q * 8];
        s16x8 a1 = *(const s16x8*)&As[16 + mi][kk * 32 + q * 8];
        acc[0] = __builtin_amdgcn_mfma_f32_16x16x32_bf16(a0, b.s, acc[0], 0, 0, 0);
        acc[1] = __builtin_amdgcn_mfma_f32_16x16x32_bf16(a1, b.s, acc[1], 0, 0, 0);
    }
}

__device__ __forceinline__ void loadA(unsigned short (*As)[1032],
                                      const unsigned short* __restrict__ src,
                                      int ldsrc, int tid) {
    #pragma unroll
    for (int i = 0; i < 16; ++i) {
        int e = (i * 256 + tid) * 8;
        int rowi = e >> 10, col = e & 1023;
        *(float4*)&As[rowi][col] = *(const float4*)(src + (size_t)rowi * ldsrc + col);
    }
}

// ---------------------------------------------------------------- persistent col-split scan
// XCD-group cg owns h-column slice [cg*128, cg*128+128) for ALL 256 batch rows.
// Per-XCD L2-resident weights ~2MB < 4MB L2 (proven R2: FETCH 10x drop).
// R5: all cross-XCD consumers use NORMAL loads on per-step virgin buffers
// (post1cT, zidxT); producers use wide u64 write-through AST. No atomic loads
// in the data path.
struct ScanP {
    const unsigned short *WhT, *Wq1aT, *Wq2T, *WizBF, *Eq;
    const float *Wi, *bi, *bh, *bq2, *gum;
    const int *act_idx;
    unsigned short *XZ, *post1cT, *postL;
    float *ghbuf, *h_st;
    int *zidxT;
    int *bar;
};

__global__ __launch_bounds__(256, 2) void k_scan(ScanP P) {
    __shared__ __align__(16) unsigned short As[32][1032];   // 66 KB
    __shared__ __align__(16) unsigned short Ps[32][64];     // 4 KB stage for post1 flush
    __shared__ int zsA[4][32];
    __shared__ int zact[4];
    __shared__ float scrW[256];
    __shared__ int sh_rank, sh_xcc, sh_cnt[8];
    int tid = threadIdx.x;
    int lane = tid & 63, wv = tid >> 6;
    int mi = lane & 15, q = lane >> 4;
    int* bar = P.bar;

    // ---- census: group = physical XCD
    if (tid == 0) {
        int xcc;
        asm volatile("s_getreg_b32 %0, hwreg(HW_REG_XCC_ID)" : "=s"(xcc));
        xcc &= 7;
        sh_xcc = xcc;
        sh_rank = atomicAdd(&bar[CNT_OFF + xcc], 1);
    }
    __syncthreads();
    int grp = sh_xcc, rank = sh_rank;

    // ---- entry barrier = epoch 1 of the unified barrier
    gbar(bar, grp, 1);

    if (tid < 8)
        sh_cnt[tid] = ALD(&bar[CNT_OFF + tid]);
    __syncthreads();
    int nb = sh_cnt[grp];
    int kg = 0, jg = 0;
    #pragma unroll
    for (int g = 0; g < 8; ++g) {
        if (sh_cnt[g] > 0) { if (g == grp) jg = kg; ++kg; }
    }
    int mych[8], nchunk = 0;
    for (int c = jg; c < 8; c += kg) mych[nchunk++] = c;

    int ep = 1;
    for (int t = 1; t <= TT; ++t) {
        // ---------- S_A: GRU; group owns h-cols [cg*128..+128), unit = 4 rows
        for (int ci = 0; ci < nchunk; ++ci) {
            int cg = mych[ci];
            int cb = cg * 128;
            for (int u = rank; u < 64; u += nb) {
                int r0 = u * 4;
                __syncthreads();
                if (tid < 128) {
                    int lr = tid >> 5, cc = tid & 31;
                    if (t > 1)
                        zsA[lr][cc] = cc * 32 +
                            P.zidxT[(t - 1) * SLOTZ + (r0 + lr) * 32 + cc];  // virgin/step
                }
                if (tid < 4)
                    zact[tid] = 1024 + P.act_idx[(t - 1) * 256 + r0 + tid];
                __syncthreads();
                int rr = tid >> 6, ln = tid & 63;
                int grow = r0 + rr;
                int j0 = cb + ln * 2;
                float g0v[2] = {0.f, 0.f};
                float g1v[2] = {0.f, 0.f};
                float g2v[2] = {0.f, 0.f};
                if (t > 1) {
                    #pragma unroll 4
                    for (int cc = 0; cc < 32; ++cc) {
                        const unsigned short* wr =
                            P.WizBF + (size_t)zsA[rr][cc] * G3 + j0;
                        unsigned int w0 = *(const unsigned int*)wr;
                        unsigned int w1 = *(const unsigned int*)(wr + 1024);
                        unsigned int w2 = *(const unsigned int*)(wr + 2048);
                        g0v[0] += bf2f((unsigned short)w0);
                        g0v[1] += bf2f((unsigned short)(w0 >> 16));
                        g1v[0] += bf2f((unsigned short)w1);
                        g1v[1] += bf2f((unsigned short)(w1 >> 16));
                        g2v[0] += bf2f((unsigned short)w2);
                        g2v[1] += bf2f((unsigned short)(w2 >> 16));
                    }
                }
                const float* wa = P.Wi + (size_t)zact[rr] * G3;
                float2 bi0 = *(const float2*)(P.bi + j0);
                float2 bi1 = *(const float2*)(P.bi + 1024 + j0);
                float2 bi2 = *(const float2*)(P.bi + 2048 + j0);
                float2 wa0 = *(const float2*)(wa + j0);
                float2 wa1 = *(const float2*)(wa + 1024 + j0);
                float2 wa2 = *(const float2*)(wa + 2048 + j0);
                g0v[0] += bi0.x + wa0.x; g0v[1] += bi0.y + wa0.y;
                g1v[0] += bi1.x + wa1.x; g1v[1] += bi1.y + wa1.y;
                g2v[0] += bi2.x + wa2.x; g2v[1] += bi2.y + wa2.y;
                const float* ghs = (t == 1) ? P.bh : (P.ghbuf + (size_t)grow * G3);
                float2 gr2 = *(const float2*)(ghs + j0);
                float2 gu2 = *(const float2*)(ghs + 1024 + j0);
                float2 gn2 = *(const float2*)(ghs + 2048 + j0);
                float2 hp2 = *(const float2*)(P.h_st + (size_t)grow * HID + j0);
                float grv[2] = {gr2.x, gr2.y};
                float guv[2] = {gu2.x, gu2.y};
                float gnv[2] = {gn2.x, gn2.y};
                float hpv[2] = {hp2.x, hp2.y};
                float ho[2];
                #pragma unroll
                for (int kq = 0; kq < 2; ++kq) {
                    float rr2 = sigm(g0v[kq] + grv[kq]);
                    float uu = sigm(g1v[kq] + guv[kq]);
                    float nn = tanhf(g2v[kq] + rr2 * gnv[kq]);
                    ho[kq] = (1.f - uu) * nn + uu * hpv[kq];
                }
                *(float2*)(P.h_st + (size_t)grow * HID + j0) = make_float2(ho[0], ho[1]);
                unsigned int pk = (unsigned int)f2bf(ho[0]) |
                                  ((unsigned int)f2bf(ho[1]) << 16);
                // cross-XCD consumer (S_B loadA, virgin/step): wide write-through.
                // lane-pair pack: even lane writes its own + right neighbor's u32.
                unsigned int pk1 = __shfl_down(pk, 1);
                if (!(ln & 1)) {
                    u64 pk64 = (u64)pk | ((u64)pk1 << 32);
                    AST((u64*)(P.XZ + ((size_t)t * 256 + grow) * 2048 + j0), pk64);
                }
            }
        }
        gbar(bar, grp, ++ep);

        // ---------- S_B: unit = (jobsel 0..3, chunk 0..7, half 0..1); 64 units
        for (int ci = 0; ci < nchunk; ++ci) {
            int cg = mych[ci];
            for (int u = rank; u < 64; u += nb) {
                int jobsel = u >> 4, rem = u & 15;
                int c = rem >> 1, half = rem & 1;
                if (jobsel < 3 && t == TT) continue;
                __syncthreads();
                loadA(As, P.XZ + ((size_t)t * 256 + c * 32) * 2048, 2048, tid);
                __syncthreads();
                if (jobsel < 3) {
                    int jj = jobsel * 8 + cg;
                    int base_n = jj * 128 + half * 64;
                    floatx4 z4 = {0.f, 0.f, 0.f, 0.f};
                    floatx4 acc[2] = {z4, z4};
                    gemm_tile16(As, P.WhT + (size_t)base_n * 1024, lane, wv, acc);
                    int col = base_n + wv * 16 + mi;
                    float bb = P.bh[col];
                    #pragma unroll
                    for (int mt = 0; mt < 2; ++mt)
                        #pragma unroll
                        for (int rg = 0; rg < 4; ++rg) {
                            int grow = c * 32 + mt * 16 + q * 4 + rg;
                            P.ghbuf[(size_t)grow * G3 + col] = acc[mt][rg] + bb;
                        }
                } else {
                    int base_n = cg * 128 + half * 64;
                    int col = base_n + wv * 16 + mi;
                    // prefetch Eq adds before GEMM (latency hides under MFMA)
                    unsigned short pe[2][4];
                    #pragma unroll
                    for (int mt = 0; mt < 2; ++mt)
                        #pragma unroll
                        for (int rg = 0; rg < 4; ++rg) {
                            int grow = c * 32 + mt * 16 + q * 4 + rg;
                            pe[mt][rg] = __builtin_nontemporal_load(
                                P.Eq + ((size_t)(t - 1) * 256 + grow) * 1024 + col);
                        }
                    floatx4 z4 = {0.f, 0.f, 0.f, 0.f};
                    floatx4 acc[2] = {z4, z4};
                    gemm_tile16(As, P.Wq1aT + (size_t)base_n * 1024, lane, wv, acc);
                    // stage tile in LDS, then flush as wide u64 write-through
                    #pragma unroll
                    for (int mt = 0; mt < 2; ++mt)
                        #pragma unroll
                        for (int rg = 0; rg < 4; ++rg) {
                            int lr = mt * 16 + q * 4 + rg;
                            float v = elu1(acc[mt][rg] + bf2f(pe[mt][rg]));
                            Ps[lr][wv * 16 + mi] = f2bf(v);
                        }
                    __syncthreads();
                    unsigned short* dst = P.post1cT + (size_t)t * SLOTP +
                                          (size_t)(c * 32) * 1024 + base_n;
                    const u64* ps = (const u64*)&Ps[0][0];
                    #pragma unroll
                    for (int w = 0; w < 2; ++w) {
                        int j2 = tid * 2 + w;
                        int row = j2 >> 4, c4 = j2 & 15;
                        AST((u64*)(dst + (size_t)row * 1024 + c4 * 4),
                            ps[row * 16 + c4]);
                    }
                }
            }
        }
        gbar(bar, grp, ++ep);

        // ---------- S_C: unit = (chunk 0..7, half 0..1); 16 units
        for (int ci = 0; ci < nchunk; ++ci) {
            int cg = mych[ci];
            for (int u = rank; u < 16; u += nb) {
                int c = u >> 1, half = u & 1;
                __syncthreads();
                loadA(As, P.post1cT + (size_t)t * SLOTP + (size_t)c * 32768, 1024, tid);
                __syncthreads();
                int base_n = cg * 128 + half * 64;
                int cat = cg * 4 + half * 2 + (wv >> 1);
                int half16 = wv & 1;
                // prefetch gumbel before GEMM
                float pg[2][4];
                #pragma unroll
                for (int mt = 0; mt < 2; ++mt)
                    #pragma unroll
                    for (int rg = 0; rg < 4; ++rg) {
                        int grow = c * 32 + mt * 16 + q * 4 + rg;
                        pg[mt][rg] = __builtin_nontemporal_load(
                            P.gum + ((size_t)(t - 1) * 256 + grow) * 1024 +
                            cat * 32 + half16 * 16 + mi);
                    }
                floatx4 z4 = {0.f, 0.f, 0.f, 0.f};
                floatx4 acc[2] = {z4, z4};
                gemm_tile16(As, P.Wq2T + (size_t)base_n * 1024, lane, wv, acc);
                int col = base_n + wv * 16 + mi;
                float bb = P.bq2[col];
                #pragma unroll
                for (int mt = 0; mt < 2; ++mt)
                    #pragma unroll
                    for (int rg = 0; rg < 4; ++rg) {
                        acc[mt][rg] += bb;
                        int grow = c * 32 + mt * 16 + q * 4 + rg;
                        __builtin_nontemporal_store(f2bf(acc[mt][rg]),
                            P.postL + ((size_t)(t - 1) * 256 + grow) * 1024 + col);
                    }
                // local argmax over this wave's 16 cols (half-category)
                float fbv[2][4]; int fcl[2][4];
                #pragma unroll
                for (int mt = 0; mt < 2; ++mt) {
                    #pragma unroll
                    for (int rg = 0; rg < 4; ++rg) {
                        float bv = acc[mt][rg] + pg[mt][rg];
                        int cls = half16 * 16 + mi;
                        #pragma unroll
                        for (int off = 1; off < 16; off <<= 1) {
                            float ov = __shfl_xor(bv, off);
                            int oc = __shfl_xor(cls, off);
                            if (ov > bv || (ov == bv && oc < cls)) { bv = ov; cls = oc; }
                        }
                        fbv[mt][rg] = bv; fcl[mt][rg] = cls;
                        if (mi == 0) {
                            float2* w = (float2*)&scrW[((wv * 4 + q) * 8 + mt * 4 + rg) * 2];
                            *w = make_float2(bv, __int_as_float(cls));
                        }
                    }
                }
                __syncthreads();
                int pw = wv ^ 1;
                #pragma unroll
                for (int mt = 0; mt < 2; ++mt) {
                    #pragma unroll
                    for (int rg = 0; rg < 4; ++rg) {
                        float2 o = *(const float2*)&scrW[((pw * 4 + q) * 8 + mt * 4 + rg) * 2];
                        float bv = fbv[mt][rg]; int cls = fcl[mt][rg];
                        int oc = __float_as_int(o.y);
                        if (o.x > bv || (o.x == bv && oc < cls)) { bv = o.x; cls = oc; }
                        int grow = c * 32 + mt * 16 + q * 4 + rg;
                        unsigned short* zo =
                            P.XZ + ((size_t)t * 256 + grow) * 2048 + 1024 + cat * 32;
                        zo[half16 * 16 + mi] = (half16 * 16 + mi == cls) ? 0x3F80 : 0;
                        if (half16 == 0 && mi == 0)
                            AST(&P.zidxT[t * SLOTZ + grow * 32 + cat], cls);  // next S_A
                    }
                }
            }
        }
        gbar(bar, grp, ++ep);
    }
}

// ---------------------------------------------------------------- KL (deferred)
__global__ void k_kl(const unsigned short* __restrict__ postL,
                     const unsigned short* __restrict__ priorL,
                     float* __restrict__ kl_acc) {
    int g = blockIdx.x * 256 + threadIdx.x;
    int sidx = g >> 5, cat = g & 31;
    const unsigned short* ql = postL + (size_t)sidx * ZD + cat * NCLS;
    const unsigned short* pl = priorL + (size_t)sidx * ZD + cat * NCLS;
    float vq[32], vp[32];
    float mq = -1e30f, mp = -1e30f;
    #pragma unroll
    for (int i = 0; i < NCLS; ++i) {
        vq[i] = bf2f(ql[i]); vp[i] = bf2f(pl[i]);
        mq = fmaxf(mq, vq[i]); mp = fmaxf(mp, vp[i]);
    }
    float sq = 0.f, sp = 0.f;
    #pragma unroll
    for (int i = 0; i < NCLS; ++i) { sq += expf(vq[i] - mq); sp += expf(vp[i] - mp); }
    float lseq = mq + logf(sq), lsep = mp + logf(sp);
    float kl = 0.f;
    #pragma unroll
    for (int i = 0; i < NCLS; ++i) {
        float lpq = vq[i] - lseq;
        kl += expf(lpq) * (lpq - (vp[i] - lsep));
    }
    __shared__ float red[256];
    red[threadIdx.x] = kl;
    __syncthreads();
    for (int s = 128; s > 0; s >>= 1) {
        if ((int)threadIdx.x < s) red[threadIdx.x] += red[threadIdx.x + s];
        __syncthreads();
    }
    if (threadIdx.x == 0) atomicAdd(&kl_acc[sidx >> 8], red[0]);
}

// ---------------------------------------------------------------- CE over 512 logits
__global__ void k_ce(const unsigned short* __restrict__ logits,
                     const int* __restrict__ obs_idx, float* __restrict__ ce_acc) {
    int s = (blockIdx.x * 256 + threadIdx.x) >> 6;
    int lane = threadIdx.x & 63;
    union { float4 f4; unsigned short u[8]; } raw;
    raw.f4 = *(const float4*)(logits + (size_t)s * OBS + lane * 8);
    float v[8];
    float m = -1e30f;
    #pragma unroll
    for (int i = 0; i < 8; ++i) { v[i] = bf2f(raw.u[i]); m = fmaxf(m, v[i]); }
    #pragma unroll
    for (int off = 32; off > 0; off >>= 1) m = fmaxf(m, __shfl_xor(m, off));
    float sum = 0.f;
    #pragma unroll
    for (int i = 0; i < 8; ++i) sum += expf(v[i] - m);
    #pragma unroll
    for (int off = 32; off > 0; off >>= 1) sum += __shfl_xor(sum, off);
    float lse = m + logf(sum);
    int tgt = obs_idx[s];
    float tv = 0.f;
    #pragma unroll
    for (int i = 0; i < 8; ++i) if (lane * 8 + i == tgt) tv = v[i];
    #pragma unroll
    for (int off = 32; off > 0; off >>= 1) tv += __shfl_xor(tv, off);
    if (lane == 0) atomicAdd(&ce_acc[s >> 8], lse - tv);
}

// ---------------------------------------------------------------- reward / continue heads
__global__ void k_heads(const unsigned short* __restrict__ dec1,
                        const float* __restrict__ Wr2, const float* __restrict__ br2,
                        const float* __restrict__ Wc2, const float* __restrict__ bc2,
                        const float* __restrict__ rew, const float* __restrict__ done,
                        float* __restrict__ mse_acc, float* __restrict__ bce_acc) {
    int s = (blockIdx.x * 256 + threadIdx.x) >> 6;
    int lane = threadIdx.x & 63;
    float vr = bf2f(dec1[(size_t)s * 192 + 64 + lane]) * Wr2[lane];
    float vc = bf2f(dec1[(size_t)s * 192 + 128 + lane]) * Wc2[lane];
    #pragma unroll
    for (int off = 32; off > 0; off >>= 1) {
        vr += __shfl_xor(vr, off);
        vc += __shfl_xor(vc, off);
    }
    if (lane == 0) {
        float r_pred = vr + br2[0], c_pred = vc + bc2[0];
        float rt = rew[s];
        float sgn = (rt > 0.f) ? 1.f : ((rt < 0.f) ? -1.f : 0.f);
        float r_tgt = sgn * log1pf(fabsf(rt));
        float d = r_pred - r_tgt;
        float ct = 1.f - done[s];
        float bce = fmaxf(c_pred, 0.f) - c_pred * ct + log1pf(expf(-fabsf(c_pred)));
        atomicAdd(&mse_acc[s >> 8], d * d);
        atomicAdd(&bce_acc[s >> 8], bce);
    }
}

// ---------------------------------------------------------------- final reduce
__global__ void k_final(const float* __restrict__ ce_acc, const float* __restrict__ mse_acc,
                        const float* __restrict__ bce_acc, const float* __restrict__ kl_acc,
                        float* __restrict__ out) {
    int t = threadIdx.x;
    float ce = ce_acc[t] * (1.f / 256.f);
    float ms = mse_acc[t] * (1.f / 256.f);
    float bc = bce_acc[t] * (1.f / 256.f);
    float ka = kl_acc[t] * (1.f / 256.f);
    float kt = fmaxf(ka, 1.f);
    #pragma unroll
    for (int off = 32; off > 0; off >>= 1) {
        ce += __shfl_down(ce, off);
        ms += __shfl_down(ms, off);
        bc += __shfl_down(bc, off);
        kt += __shfl_down(kt, off);
    }
    if (t == 0) {
        ce *= (1.f / 64.f); ms *= (1.f / 64.f); bc *= (1.f / 64.f); kt *= (1.f / 64.f);
        out[0] = ce + ms + bc + kt;
        out[1] = ce; out[2] = ms; out[3] = bc; out[4] = kt;
    }
}

// ----------------------------------------------------------------------------------
extern "C" void kernel_launch(void* const* d_in, const int* in_sizes, int n_in,
                              void* d_out, int out_size, void* d_ws, size_t ws_size,
                              hipStream_t stream) {
    const float* obs  = (const float*)d_in[0];
    const float* act  = (const float*)d_in[1];
    const float* rew  = (const float*)d_in[2];
    const float* done = (const float*)d_in[3];
    const float* gum  = (const float*)d_in[4];
    const float* We1  = (const float*)d_in[5];
    const float* be1  = (const float*)d_in[6];
    const float* We2  = (const float*)d_in[7];
    const float* be2  = (const float*)d_in[8];
    const float* Wi   = (const float*)d_in[9];
    const float* Wh   = (const float*)d_in[10];
    const float* bi   = (const float*)d_in[11];
    const float* bh   = (const float*)d_in[12];
    const float* Wp1  = (const float*)d_in[13];
    const float* bp1  = (const float*)d_in[14];
    const float* Wp2  = (const float*)d_in[15];
    const float* bp2  = (const float*)d_in[16];
    const float* Wq1  = (const float*)d_in[17];
    const float* bq1  = (const float*)d_in[18];
    const float* Wq2  = (const float*)d_in[19];
    const float* bq2  = (const float*)d_in[20];
    const float* Wd1  = (const float*)d_in[21];
    const float* bd1  = (const float*)d_in[22];
    const float* Wd2  = (const float*)d_in[23];
    const float* bd2  = (const float*)d_in[24];
    const float* Wr1  = (const float*)d_in[25];
    const float* br1  = (const float*)d_in[26];
    const float* Wr2  = (const float*)d_in[27];
    const float* br2  = (const float*)d_in[28];
    const float* Wc1  = (const float*)d_in[29];
    const float* bc1  = (const float*)d_in[30];
    const float* Wc2  = (const float*)d_in[31];
    const float* bc2  = (const float*)d_in[32];

    char* base = (char*)d_ws;
    size_t off = 0;
    auto alloc = [&](size_t bytes) -> char* {
        char* p = base + off;
        off += (bytes + 255) & ~(size_t)255;
        return p;
    };
    unsigned short* WhT   = (unsigned short*)alloc(3072u * 1024 * 2);
    unsigned short* WizBF = (unsigned short*)alloc(1024u * 3072 * 2);
    unsigned short* Wq1aT = (unsigned short*)alloc(1024u * 1024 * 2);
    unsigned short* Wq1bT = (unsigned short*)alloc(1024u * 512 * 2);
    unsigned short* Wq2T  = (unsigned short*)alloc(1024u * 1024 * 2);
    unsigned short* Wp1T  = (unsigned short*)alloc(1024u * 1024 * 2);
    unsigned short* Wp2T  = (unsigned short*)alloc(1024u * 1024 * 2);
    unsigned short* WdrcT = (unsigned short*)alloc(192u * 2048 * 2);
    unsigned short* Wd2T  = (unsigned short*)alloc(512u * 64 * 2);
    unsigned short* We2T  = (unsigned short*)alloc(512u * 64 * 2);
    float*          b_drc = (float*)alloc(192 * 4);
    unsigned short* XZ    = (unsigned short*)alloc(65u * 256 * 2048 * 2);   // 68 MB
    float*          h_st  = (float*)alloc(256u * 1024 * 4);
    float*          ghbuf = (float*)alloc(256u * 3072 * 4);
    unsigned short* post1cT = (unsigned short*)alloc(65u * SLOTP * 2);      // 34 MB per-step
    int*            zidxT = (int*)alloc(65u * SLOTZ * 4);                   // 2.1 MB per-step
    unsigned short* postL = (unsigned short*)alloc(16384u * 1024 * 2);      // 32 MB (reused: logits)
    unsigned short* Eq    = (unsigned short*)alloc(16384u * 1024 * 2);      // 32 MB (reused: priorL)
    unsigned short* pri1  = (unsigned short*)alloc(16384u * 1024 * 2);      // 32 MB
    unsigned short* dec1  = (unsigned short*)alloc(16384u * 192 * 2);
    float*          acc   = (float*)alloc(256 * 4);
    int*            obs_idx = (int*)alloc(16384 * 4);
    int*            act_idx = (int*)alloc(16384 * 4);
    int*            bar     = (int*)alloc(BAR_INTS * 4);
    unsigned short* embed = pri1;                    // setup-time aliases (pri1 unused then)
    unsigned short* e1    = pri1 + 16384u * 512;

    hipMemsetAsync(h_st, 0, 256u * 1024 * 4, stream);
    hipMemsetAsync(acc, 0, 256 * 4, stream);
    hipMemsetAsync(bar, 0, BAR_INTS * 4, stream);

    k_idx<<<4096, 256, 0, stream>>>(obs, act, obs_idx, act_idx);

    dim3 tb(32, 8);
    k_transp<<<dim3(96, 32), tb, 0, stream>>>(Wh, 3072, WhT, 1024, 0);
    k_cast<<<(1024 * 3072) / 256, 256, 0, stream>>>(Wi, WizBF, 1024 * 3072);
    k_transp<<<dim3(32, 32), tb, 0, stream>>>(Wq1, 1024, Wq1aT, 1024, 0);
    k_transp<<<dim3(32, 16), tb, 0, stream>>>(Wq1 + 1024u * 1024, 1024, Wq1bT, 512, 0);
    k_transp<<<dim3(32, 32), tb, 0, stream>>>(Wq2, 1024, Wq2T, 1024, 0);
    k_transp<<<dim3(32, 32), tb, 0, stream>>>(Wp1, 1024, Wp1T, 1024, 0);
    k_transp<<<dim3(32, 32), tb, 0, stream>>>(Wp2, 1024, Wp2T, 1024, 0);
    k_transp<<<dim3(2, 64),  tb, 0, stream>>>(Wd1, 64, WdrcT, 2048, 0);
    k_transp<<<dim3(2, 64),  tb, 0, stream>>>(Wr1, 64, WdrcT + 64u * 2048, 2048, 0);
    k_transp<<<dim3(2, 64),  tb, 0, stream>>>(Wc1, 64, WdrcT + 128u * 2048, 2048, 0);
    k_transp<<<dim3(16, 2),  tb, 0, stream>>>(Wd2, 512, Wd2T, 64, 0);
    k_transp<<<dim3(16, 2),  tb, 0, stream>>>(We2, 512, We2T, 64, 0);
    k_pack_bias<<<1, 192, 0, stream>>>(bd1, br1, bc1, b_drc);

    // embed & Eq precompute (all 64 steps)
    k_e1<<<4096, 256, 0, stream>>>(obs_idx, We1, be1, e1);
    {
        MJob m = { e1, 64, We2T, be2, nullptr, embed, 512, 512, 64, 2 };
        mfma_gemm<<<dim3(8, 256), 256, 0, stream>>>(m);
    }
    {
        MJob m = { embed, 512, Wq1bT, bq1, nullptr, Eq, 1024, 1024, 512, 2 };
        mfma_gemm<<<dim3(16, 256), 256, 0, stream>>>(m);
    }

    // persistent col-split scan (cooperative launch for co-residency; 2 blocks/CU)
    ScanP SP;
    SP.WhT = WhT; SP.Wq1aT = Wq1aT; SP.Wq2T = Wq2T; SP.WizBF = WizBF; SP.Eq = Eq;
    SP.Wi = Wi; SP.bi = bi; SP.bh = bh; SP.bq2 = bq2; SP.gum = gum;
    SP.act_idx = act_idx;
    SP.XZ = XZ; SP.post1cT = post1cT; SP.postL = postL;
    SP.ghbuf = ghbuf; SP.h_st = h_st; SP.zidxT = zidxT; SP.bar = bar;
    void* kargs[] = { (void*)&SP };
    hipLaunchCooperativeKernel((const void*)k_scan, dim3(NBLK), dim3(256), kargs, 0, stream);

    // deferred batched passes
    unsigned short* Hall = XZ + (size_t)256 * 2048;
    {   // prior1 = elu(H @ Wp1 + bp1)
        MJob m = { Hall, 2048, Wp1T, bp1, nullptr, pri1, 1024, 1024, 1024, 1 | 2 };
        mfma_gemm<<<dim3(16, 256), 256, 0, stream>>>(m);
    }
    {   // priorL = prior1 @ Wp2 + bp2 (into Eq buffer)
        MJob m = { pri1, 1024, Wp2T, bp2, nullptr, Eq, 1024, 1024, 1024, 2 };
        mfma_gemm<<<dim3(16, 256), 256, 0, stream>>>(m);
    }
    k_kl<<<2048, 256, 0, stream>>>(postL, Eq, acc + 192);
    {
        MJob m = { Hall, 2048, WdrcT, b_drc, nullptr, dec1, 192, 192, 2048, 1 | 2 };
        mfma_gemm<<<dim3(3, 256), 256, 0, stream>>>(m);
    }
    {
        MJob m = { dec1, 192, Wd2T, bd2, nullptr, postL, 512, 512, 64, 2 };
        mfma_gemm<<<dim3(8, 256), 256, 0, stream>>>(m);
    }
    k_ce<<<4096, 256, 0, stream>>>(postL, obs_idx, acc + 0);
    k_heads<<<4096, 256, 0, stream>>>(dec1, Wr2, br2, Wc2, bc2, rew, done,
                                      acc + 64, acc + 128);
    k_final<<<1, 64, 0, stream>>>(acc + 0, acc + 64, acc + 128, acc + 192, (float*)d_out);
}

// Round 6
// 3349.321 us; speedup vs baseline: 1.7441x; 1.7375x over previous
//
#include <hip/hip_runtime.h>
#include <math.h>

#define TT 64
#define BB 256
#define OBS 512
#define ACTN 16
#define EMB 512
#define HID 1024
#define NCAT 32
#define NCLS 32
#define ZD 1024
#define G3 3072
#define NBLK 512
#define SLOTP 262144          // post1cT u16 per step slot (8*32*1024)
#define SLOTZ 8192            // zidxT ints per step slot (256*32)

typedef short s16x8 __attribute__((ext_vector_type(8)));
typedef float floatx4 __attribute__((ext_vector_type(4)));
typedef unsigned long long u64;

// barrier buffer layout (ints)
constexpr int CNT_OFF = 0;          // 8 census counters
constexpr int ARR_OFF = 16;         // 512*16 arrive slots
constexpr int REL_OFF = 16 + NBLK * 16;   // 8*16 per-XCD release lines
constexpr int BAR_INTS = REL_OFF + 8 * 16 + 16;

#define ALD(p)    __hip_atomic_load((p), __ATOMIC_RELAXED, __HIP_MEMORY_SCOPE_AGENT)
#define AST(p, v) __hip_atomic_store((p), (v), __ATOMIC_RELAXED, __HIP_MEMORY_SCOPE_AGENT)

union U64F2 { u64 u; float2 f; };

__device__ __forceinline__ unsigned short f2bf(float f) {
    unsigned int u = __float_as_uint(f);
    unsigned int r = (u + 0x7fffu + ((u >> 16) & 1u)) >> 16;
    return (unsigned short)r;
}
__device__ __forceinline__ float bf2f(unsigned short h) {
    return __uint_as_float(((unsigned int)h) << 16);
}
__device__ __forceinline__ float elu1(float v) {
    return v > 0.f ? v : (expf(v) - 1.f);
}
__device__ __forceinline__ float sigm(float v) {
    return 1.f / (1.f + expf(-v));
}

// release: drain this wave's memory ops (write-through ASTs reach coherence point)
__device__ __forceinline__ void rel_drain() {
    asm volatile("" ::: "memory");
    asm volatile("s_waitcnt vmcnt(0) lgkmcnt(0)" ::: "memory");
}

// centralized global barrier — NO acquire fence (agent acquire = buffer_inv sc1
// which invalidates clean L2 lines and evicts the L2-resident weights; every
// cross-block data path is fence-free by construction: virgin-address normal
// loads, or AST(write-through)+ALD(coherence-point) pairs).
__device__ __forceinline__ void gbar(int* bar, int grp, int ep) {
    rel_drain();
    __syncthreads();
    int tid = threadIdx.x;
    if (tid == 0)
        AST(&bar[ARR_OFF + blockIdx.x * 16], ep);
    if (blockIdx.x == 0) {
        for (int i = tid; i < NBLK; i += 256)
            while (ALD(&bar[ARR_OFF + i * 16]) < ep)
                __builtin_amdgcn_s_sleep(1);
        __syncthreads();
        if (tid < 8)
            AST(&bar[REL_OFF + tid * 16], ep);
    } else if (tid == 0) {
        while (ALD(&bar[REL_OFF + grp * 16]) < ep)
            __builtin_amdgcn_s_sleep(1);
    }
    __syncthreads();
    asm volatile("" ::: "memory");
}

// ---------------------------------------------------------------- one-hot -> index
__global__ void k_idx(const float* __restrict__ obs, const float* __restrict__ act,
                      int* __restrict__ obs_idx, int* __restrict__ act_idx) {
    int wave = (blockIdx.x * blockDim.x + threadIdx.x) >> 6;
    int lane = threadIdx.x & 63;
    if (wave >= TT * BB) return;
    const float* o = obs + (size_t)wave * OBS;
    int found = -1;
    #pragma unroll
    for (int j = 0; j < 8; ++j) {
        float v = o[lane + 64 * j];
        if (v > 0.5f) found = lane + 64 * j;
    }
    unsigned long long m = __ballot(found >= 0);
    int src = __ffsll(m) - 1;
    int oidx = __shfl(found, src);
    int af = -1;
    if (lane < ACTN) {
        float v = act[(size_t)wave * ACTN + lane];
        if (v > 0.5f) af = lane;
    }
    unsigned long long m2 = __ballot(af >= 0);
    int src2 = __ffsll(m2) - 1;
    int aidx = __shfl(af, src2);
    if (lane == 0) { obs_idx[wave] = oidx; act_idx[wave] = aidx; }
}

// ---------------------------------------------------------------- transpose fp32 -> bf16
__global__ void k_transp(const float* __restrict__ in, int instride,
                         unsigned short* __restrict__ out, int ldo, int ko) {
    __shared__ float t[32][33];
    int c0 = blockIdx.x * 32, r0 = blockIdx.y * 32;
    int tx = threadIdx.x, ty = threadIdx.y;
    #pragma unroll
    for (int i = 0; i < 4; ++i)
        t[ty + 8 * i][tx] = in[(size_t)(r0 + ty + 8 * i) * instride + c0 + tx];
    __syncthreads();
    #pragma unroll
    for (int i = 0; i < 4; ++i)
        out[(size_t)(c0 + ty + 8 * i) * ldo + ko + r0 + tx] = f2bf(t[tx][ty + 8 * i]);
}

__global__ void k_cast(const float* __restrict__ in, unsigned short* __restrict__ out, int n) {
    int i = blockIdx.x * 256 + threadIdx.x;
    if (i < n) out[i] = f2bf(in[i]);
}

__global__ void k_pack_bias(const float* bd1, const float* br1, const float* bc1,
                            float* __restrict__ out) {
    int i = threadIdx.x;
    if (i < 64) out[i] = bd1[i];
    else if (i < 128) out[i] = br1[i - 64];
    else out[i] = bc1[i - 128];
}

__global__ void k_e1(const int* __restrict__ obs_idx, const float* __restrict__ We1,
                     const float* __restrict__ be1, unsigned short* __restrict__ e1) {
    int g = blockIdx.x * 256 + threadIdx.x;
    int s = g >> 6, k = g & 63;
    float v = We1[obs_idx[s] * 64 + k] + be1[k];
    e1[g] = f2bf(elu1(v));
}

// ---------------------------------------------------------------- generic MFMA GEMM (batched)
struct MJob {
    const unsigned short* X; int ldx;
    const unsigned short* WT;
    const float* bias;
    const unsigned short* addb;
    void* out; int ldo;
    int N, K, flags;              // 1=elu, 2=bf16 out, 4=addb
};

__global__ __launch_bounds__(256) void mfma_gemm(MJob j) {
    __shared__ unsigned short Xs[64][40];
    __shared__ unsigned short Ns[64][40];
    int tid = threadIdx.x;
    int m0 = blockIdx.y * 64, n0 = blockIdx.x * 64;
    int r = tid >> 2, p = (tid & 3) * 8;
    const unsigned short* xg = j.X + (size_t)(m0 + r) * j.ldx + p;
    const unsigned short* wg = j.WT + (size_t)(n0 + r) * j.K + p;
    int lane = tid & 63, wv = tid >> 6;
    int wm = (wv & 1) * 32, wn = (wv >> 1) * 32;
    int mi = lane & 15, q = lane >> 4;
    floatx4 acc00 = {0.f, 0.f, 0.f, 0.f};
    floatx4 acc01 = acc00, acc10 = acc00, acc11 = acc00;
    for (int kt = 0; kt < j.K; kt += 32) {
        *(float4*)&Xs[r][p] = *(const float4*)(xg + kt);
        *(float4*)&Ns[r][p] = *(const float4*)(wg + kt);
        __syncthreads();
        s16x8 a0 = *(const s16x8*)&Xs[wm + mi][q * 8];
        s16x8 a1 = *(const s16x8*)&Xs[wm + 16 + mi][q * 8];
        s16x8 b0 = *(const s16x8*)&Ns[wn + mi][q * 8];
        s16x8 b1 = *(const s16x8*)&Ns[wn + 16 + mi][q * 8];
        acc00 = __builtin_amdgcn_mfma_f32_16x16x32_bf16(a0, b0, acc00, 0, 0, 0);
        acc01 = __builtin_amdgcn_mfma_f32_16x16x32_bf16(a0, b1, acc01, 0, 0, 0);
        acc10 = __builtin_amdgcn_mfma_f32_16x16x32_bf16(a1, b0, acc10, 0, 0, 0);
        acc11 = __builtin_amdgcn_mfma_f32_16x16x32_bf16(a1, b1, acc11, 0, 0, 0);
        __syncthreads();
    }
    #pragma unroll
    for (int i = 0; i < 2; ++i) {
        #pragma unroll
        for (int jj = 0; jj < 2; ++jj) {
            floatx4 a = (i == 0) ? ((jj == 0) ? acc00 : acc01)
                                 : ((jj == 0) ? acc10 : acc11);
            int col = n0 + wn + jj * 16 + mi;
            float badd = j.bias ? j.bias[col] : 0.f;
            #pragma unroll
            for (int rg = 0; rg < 4; ++rg) {
                int row = m0 + wm + i * 16 + q * 4 + rg;
                float v = a[rg] + badd;
                if (j.flags & 4) v += bf2f(j.addb[(size_t)row * j.N + col]);
                if (j.flags & 1) v = elu1(v);
                if (j.flags & 2)
                    ((unsigned short*)j.out)[(size_t)row * j.ldo + col] = f2bf(v);
                else
                    ((float*)j.out)[(size_t)row * j.ldo + col] = v;
            }
        }
    }
}

// ---------------------------------------------------------------- scan tile GEMM (64-col)
// C[32, 64] : A(LDS [32][1032], K=1024) @ WTb[64 rows][1024]^T
// wave wv (0..3) owns cols wv*16..+16. Per-lane B chain = 32 float4, prefetch depth 8.
__device__ __forceinline__ void gemm_tile16(const unsigned short (*As)[1032],
                                            const unsigned short* __restrict__ WTb,
                                            int lane, int wv, floatx4 acc[2]) {
    int mi = lane & 15, q = lane >> 4;
    const unsigned short* bg = WTb + (size_t)(wv * 16 + mi) * 1024 + q * 8;
    float4 pb[8];
    #pragma unroll
    for (int i = 0; i < 8; ++i) pb[i] = *(const float4*)(bg + i * 32);
    #pragma unroll
    for (int kk = 0; kk < 32; ++kk) {
        union { float4 f; s16x8 s; } b;
        b.f = pb[kk & 7];
        if (kk < 24) pb[kk & 7] = *(const float4*)(bg + (kk + 8) * 32);
        s16x8 a0 = *(const s16x8*)&As[mi][kk * 32 + q * 8];
        s16x8 a1 = *(const s16x8*)&As[16 + mi][kk * 32 + q * 8];
        acc[0] = __builtin_amdgcn_mfma_f32_16x16x32_bf16(a0, b.s, acc[0], 0, 0, 0);
        acc[1] = __builtin_amdgcn_mfma_f32_16x16x32_bf16(a1, b.s, acc[1], 0, 0, 0);
    }
}

__device__ __forceinline__ void loadA(unsigned short (*As)[1032],
                                      const unsigned short* __restrict__ src,
                                      int ldsrc, int tid) {
    #pragma unroll
    for (int i = 0; i < 16; ++i) {
        int e = (i * 256 + tid) * 8;
        int rowi = e >> 10, col = e & 1023;
        *(float4*)&As[rowi][col] = *(const float4*)(src + (size_t)rowi * ldsrc + col);
    }
}

// ---------------------------------------------------------------- persistent col-split scan
// XCD-group cg owns h-column slice [cg*128, cg*128+128) for ALL 256 batch rows.
// Per-XCD L2-resident weights ~2MB < 4MB L2 (proven R2: FETCH 10x drop).
// R6: NO acquire fence anywhere in the loop -> weight lines survive in L2 all
// 64 steps. Cross-block data: virgin-address buffers (XZ/post1cT/zidxT) via
// AST-producer + normal-virgin-consumer; reused-address ghbuf via AST + ALD.
struct ScanP {
    const unsigned short *WhT, *Wq1aT, *Wq2T, *WizBF, *Eq;
    const float *Wi, *bi, *bh, *bq2, *gum;
    const int *act_idx;
    unsigned short *XZ, *post1cT, *postL;
    float *ghbuf, *h_st;
    int *zidxT;
    int *bar;
};

__global__ __launch_bounds__(256, 2) void k_scan(ScanP P) {
    __shared__ __align__(16) unsigned short As[32][1032];   // 66 KB
    __shared__ __align__(16) float StgF[32][64];            // 8 KB stage (gh fp32 / post u16)
    __shared__ int zsA[4][32];
    __shared__ int zact[4];
    __shared__ float scrW[256];
    __shared__ int sh_rank, sh_xcc, sh_cnt[8];
    int tid = threadIdx.x;
    int lane = tid & 63, wv = tid >> 6;
    int mi = lane & 15, q = lane >> 4;
    int* bar = P.bar;
    unsigned short (*Ps)[64] = (unsigned short (*)[64])StgF;   // u16 alias of stage

    // ---- census: group = physical XCD
    if (tid == 0) {
        int xcc;
        asm volatile("s_getreg_b32 %0, hwreg(HW_REG_XCC_ID)" : "=s"(xcc));
        xcc &= 7;
        sh_xcc = xcc;
        sh_rank = atomicAdd(&bar[CNT_OFF + xcc], 1);
    }
    __syncthreads();
    int grp = sh_xcc, rank = sh_rank;

    // ---- entry barrier = epoch 1 of the unified barrier
    gbar(bar, grp, 1);

    if (tid < 8)
        sh_cnt[tid] = ALD(&bar[CNT_OFF + tid]);
    __syncthreads();
    int nb = sh_cnt[grp];
    int kg = 0, jg = 0;
    #pragma unroll
    for (int g = 0; g < 8; ++g) {
        if (sh_cnt[g] > 0) { if (g == grp) jg = kg; ++kg; }
    }
    int mych[8], nchunk = 0;
    for (int c = jg; c < 8; c += kg) mych[nchunk++] = c;

    int ep = 1;
    for (int t = 1; t <= TT; ++t) {
        // ---------- S_A: GRU; group owns h-cols [cg*128..+128), unit = 4 rows
        for (int ci = 0; ci < nchunk; ++ci) {
            int cg = mych[ci];
            int cb = cg * 128;
            for (int u = rank; u < 64; u += nb) {
                int r0 = u * 4;
                __syncthreads();
                if (tid < 128) {
                    int lr = tid >> 5, cc = tid & 31;
                    if (t > 1)
                        zsA[lr][cc] = cc * 32 +
                            P.zidxT[(t - 1) * SLOTZ + (r0 + lr) * 32 + cc];  // virgin/step
                }
                if (tid < 4)
                    zact[tid] = 1024 + P.act_idx[(t - 1) * 256 + r0 + tid];
                __syncthreads();
                int rr = tid >> 6, ln = tid & 63;
                int grow = r0 + rr;
                int j0 = cb + ln * 2;
                float g0v[2] = {0.f, 0.f};
                float g1v[2] = {0.f, 0.f};
                float g2v[2] = {0.f, 0.f};
                if (t > 1) {
                    #pragma unroll 4
                    for (int cc = 0; cc < 32; ++cc) {
                        const unsigned short* wr =
                            P.WizBF + (size_t)zsA[rr][cc] * G3 + j0;
                        unsigned int w0 = *(const unsigned int*)wr;
                        unsigned int w1 = *(const unsigned int*)(wr + 1024);
                        unsigned int w2 = *(const unsigned int*)(wr + 2048);
                        g0v[0] += bf2f((unsigned short)w0);
                        g0v[1] += bf2f((unsigned short)(w0 >> 16));
                        g1v[0] += bf2f((unsigned short)w1);
                        g1v[1] += bf2f((unsigned short)(w1 >> 16));
                        g2v[0] += bf2f((unsigned short)w2);
                        g2v[1] += bf2f((unsigned short)(w2 >> 16));
                    }
                }
                const float* wa = P.Wi + (size_t)zact[rr] * G3;
                float2 bi0 = *(const float2*)(P.bi + j0);
                float2 bi1 = *(const float2*)(P.bi + 1024 + j0);
                float2 bi2 = *(const float2*)(P.bi + 2048 + j0);
                float2 wa0 = *(const float2*)(wa + j0);
                float2 wa1 = *(const float2*)(wa + 1024 + j0);
                float2 wa2 = *(const float2*)(wa + 2048 + j0);
                g0v[0] += bi0.x + wa0.x; g0v[1] += bi0.y + wa0.y;
                g1v[0] += bi1.x + wa1.x; g1v[1] += bi1.y + wa1.y;
                g2v[0] += bi2.x + wa2.x; g2v[1] += bi2.y + wa2.y;
                // gh: reused addresses, written via AST (coherence point) ->
                // read via ALD; t==1 reads the read-only bias instead.
                float2 gr2, gu2, gn2;
                if (t == 1) {
                    gr2 = *(const float2*)(P.bh + j0);
                    gu2 = *(const float2*)(P.bh + 1024 + j0);
                    gn2 = *(const float2*)(P.bh + 2048 + j0);
                } else {
                    const float* ghs = P.ghbuf + (size_t)grow * G3;
                    U64F2 a0, a1, a2;
                    a0.u = ALD((const u64*)(ghs + j0));
                    a1.u = ALD((const u64*)(ghs + 1024 + j0));
                    a2.u = ALD((const u64*)(ghs + 2048 + j0));
                    gr2 = a0.f; gu2 = a1.f; gn2 = a2.f;
                }
                float2 hp2 = *(const float2*)(P.h_st + (size_t)grow * HID + j0);
                float grv[2] = {gr2.x, gr2.y};
                float guv[2] = {gu2.x, gu2.y};
                float gnv[2] = {gn2.x, gn2.y};
                float hpv[2] = {hp2.x, hp2.y};
                float ho[2];
                #pragma unroll
                for (int kq = 0; kq < 2; ++kq) {
                    float rr2 = sigm(g0v[kq] + grv[kq]);
                    float uu = sigm(g1v[kq] + guv[kq]);
                    float nn = tanhf(g2v[kq] + rr2 * gnv[kq]);
                    ho[kq] = (1.f - uu) * nn + uu * hpv[kq];
                }
                *(float2*)(P.h_st + (size_t)grow * HID + j0) = make_float2(ho[0], ho[1]);
                unsigned int pk = (unsigned int)f2bf(ho[0]) |
                                  ((unsigned int)f2bf(ho[1]) << 16);
                // cross-XCD consumer (S_B loadA, virgin/step): wide write-through.
                unsigned int pk1 = __shfl_down(pk, 1);
                if (!(ln & 1)) {
                    u64 pk64 = (u64)pk | ((u64)pk1 << 32);
                    AST((u64*)(P.XZ + ((size_t)t * 256 + grow) * 2048 + j0), pk64);
                }
            }
        }
        gbar(bar, grp, ++ep);

        // ---------- S_B: unit = (jobsel 0..3, chunk 0..7, half 0..1); 64 units
        for (int ci = 0; ci < nchunk; ++ci) {
            int cg = mych[ci];
            for (int u = rank; u < 64; u += nb) {
                int jobsel = u >> 4, rem = u & 15;
                int c = rem >> 1, half = rem & 1;
                if (jobsel < 3 && t == TT) continue;
                __syncthreads();
                loadA(As, P.XZ + ((size_t)t * 256 + c * 32) * 2048, 2048, tid);
                __syncthreads();
                if (jobsel < 3) {
                    int jj = jobsel * 8 + cg;
                    int base_n = jj * 128 + half * 64;
                    floatx4 z4 = {0.f, 0.f, 0.f, 0.f};
                    floatx4 acc[2] = {z4, z4};
                    gemm_tile16(As, P.WhT + (size_t)base_n * 1024, lane, wv, acc);
                    int col = base_n + wv * 16 + mi;
                    float bb = P.bh[col];
                    // stage fp32 tile in LDS, flush as wide u64 write-through
                    // (ghbuf addresses are reused across steps -> must live at
                    // the coherence point; consumer reads via ALD)
                    #pragma unroll
                    for (int mt = 0; mt < 2; ++mt)
                        #pragma unroll
                        for (int rg = 0; rg < 4; ++rg) {
                            int lr = mt * 16 + q * 4 + rg;
                            StgF[lr][wv * 16 + mi] = acc[mt][rg] + bb;
                        }
                    __syncthreads();
                    {
                        const u64* gs = (const u64*)&StgF[0][0];
                        float* dstg = P.ghbuf + (size_t)(c * 32) * G3 + base_n;
                        #pragma unroll
                        for (int w = 0; w < 4; ++w) {
                            int idx = tid * 4 + w;
                            int row = idx >> 5, c8 = idx & 31;
                            AST((u64*)(dstg + (size_t)row * G3 + c8 * 2),
                                gs[row * 32 + c8]);
                        }
                    }
                } else {
                    int base_n = cg * 128 + half * 64;
                    int col = base_n + wv * 16 + mi;
                    // prefetch Eq adds before GEMM (latency hides under MFMA)
                    unsigned short pe[2][4];
                    #pragma unroll
                    for (int mt = 0; mt < 2; ++mt)
                        #pragma unroll
                        for (int rg = 0; rg < 4; ++rg) {
                            int grow = c * 32 + mt * 16 + q * 4 + rg;
                            pe[mt][rg] = __builtin_nontemporal_load(
                                P.Eq + ((size_t)(t - 1) * 256 + grow) * 1024 + col);
                        }
                    floatx4 z4 = {0.f, 0.f, 0.f, 0.f};
                    floatx4 acc[2] = {z4, z4};
                    gemm_tile16(As, P.Wq1aT + (size_t)base_n * 1024, lane, wv, acc);
                    // stage tile in LDS, then flush as wide u64 write-through
                    #pragma unroll
                    for (int mt = 0; mt < 2; ++mt)
                        #pragma unroll
                        for (int rg = 0; rg < 4; ++rg) {
                            int lr = mt * 16 + q * 4 + rg;
                            float v = elu1(acc[mt][rg] + bf2f(pe[mt][rg]));
                            Ps[lr][wv * 16 + mi] = f2bf(v);
                        }
                    __syncthreads();
                    unsigned short* dst = P.post1cT + (size_t)t * SLOTP +
                                          (size_t)(c * 32) * 1024 + base_n;
                    const u64* ps = (const u64*)&Ps[0][0];
                    #pragma unroll
                    for (int w = 0; w < 2; ++w) {
                        int j2 = tid * 2 + w;
                        int row = j2 >> 4, c4 = j2 & 15;
                        AST((u64*)(dst + (size_t)row * 1024 + c4 * 4),
                            ps[row * 16 + c4]);
                    }
                }
            }
        }
        gbar(bar, grp, ++ep);

        // ---------- S_C: unit = (chunk 0..7, half 0..1); 16 units
        for (int ci = 0; ci < nchunk; ++ci) {
            int cg = mych[ci];
            for (int u = rank; u < 16; u += nb) {
                int c = u >> 1, half = u & 1;
                __syncthreads();
                loadA(As, P.post1cT + (size_t)t * SLOTP + (size_t)c * 32768, 1024, tid);
                __syncthreads();
                int base_n = cg * 128 + half * 64;
                int cat = cg * 4 + half * 2 + (wv >> 1);
                int half16 = wv & 1;
                // prefetch gumbel before GEMM
                float pg[2][4];
                #pragma unroll
                for (int mt = 0; mt < 2; ++mt)
                    #pragma unroll
                    for (int rg = 0; rg < 4; ++rg) {
                        int grow = c * 32 + mt * 16 + q * 4 + rg;
                        pg[mt][rg] = __builtin_nontemporal_load(
                            P.gum + ((size_t)(t - 1) * 256 + grow) * 1024 +
                            cat * 32 + half16 * 16 + mi);
                    }
                floatx4 z4 = {0.f, 0.f, 0.f, 0.f};
                floatx4 acc[2] = {z4, z4};
                gemm_tile16(As, P.Wq2T + (size_t)base_n * 1024, lane, wv, acc);
                int col = base_n + wv * 16 + mi;
                float bb = P.bq2[col];
                #pragma unroll
                for (int mt = 0; mt < 2; ++mt)
                    #pragma unroll
                    for (int rg = 0; rg < 4; ++rg) {
                        acc[mt][rg] += bb;
                        int grow = c * 32 + mt * 16 + q * 4 + rg;
                        __builtin_nontemporal_store(f2bf(acc[mt][rg]),
                            P.postL + ((size_t)(t - 1) * 256 + grow) * 1024 + col);
                    }
                // local argmax over this wave's 16 cols (half-category)
                float fbv[2][4]; int fcl[2][4];
                #pragma unroll
                for (int mt = 0; mt < 2; ++mt) {
                    #pragma unroll
                    for (int rg = 0; rg < 4; ++rg) {
                        float bv = acc[mt][rg] + pg[mt][rg];
                        int cls = half16 * 16 + mi;
                        #pragma unroll
                        for (int off = 1; off < 16; off <<= 1) {
                            float ov = __shfl_xor(bv, off);
                            int oc = __shfl_xor(cls, off);
                            if (ov > bv || (ov == bv && oc < cls)) { bv = ov; cls = oc; }
                        }
                        fbv[mt][rg] = bv; fcl[mt][rg] = cls;
                        if (mi == 0) {
                            float2* w = (float2*)&scrW[((wv * 4 + q) * 8 + mt * 4 + rg) * 2];
                            *w = make_float2(bv, __int_as_float(cls));
                        }
                    }
                }
                __syncthreads();
                int pw = wv ^ 1;
                #pragma unroll
                for (int mt = 0; mt < 2; ++mt) {
                    #pragma unroll
                    for (int rg = 0; rg < 4; ++rg) {
                        float2 o = *(const float2*)&scrW[((pw * 4 + q) * 8 + mt * 4 + rg) * 2];
                        float bv = fbv[mt][rg]; int cls = fcl[mt][rg];
                        int oc = __float_as_int(o.y);
                        if (o.x > bv || (o.x == bv && oc < cls)) { bv = o.x; cls = oc; }
                        int grow = c * 32 + mt * 16 + q * 4 + rg;
                        unsigned short* zo =
                            P.XZ + ((size_t)t * 256 + grow) * 2048 + 1024 + cat * 32;
                        zo[half16 * 16 + mi] = (half16 * 16 + mi == cls) ? 0x3F80 : 0;
                        if (half16 == 0 && mi == 0)
                            AST(&P.zidxT[t * SLOTZ + grow * 32 + cat], cls);  // next S_A
                    }
                }
            }
        }
        gbar(bar, grp, ++ep);
    }
}

// ---------------------------------------------------------------- KL (deferred)
__global__ void k_kl(const unsigned short* __restrict__ postL,
                     const unsigned short* __restrict__ priorL,
                     float* __restrict__ kl_acc) {
    int g = blockIdx.x * 256 + threadIdx.x;
    int sidx = g >> 5, cat = g & 31;
    const unsigned short* ql = postL + (size_t)sidx * ZD + cat * NCLS;
    const unsigned short* pl = priorL + (size_t)sidx * ZD + cat * NCLS;
    float vq[32], vp[32];
    float mq = -1e30f, mp = -1e30f;
    #pragma unroll
    for (int i = 0; i < NCLS; ++i) {
        vq[i] = bf2f(ql[i]); vp[i] = bf2f(pl[i]);
        mq = fmaxf(mq, vq[i]); mp = fmaxf(mp, vp[i]);
    }
    float sq = 0.f, sp = 0.f;
    #pragma unroll
    for (int i = 0; i < NCLS; ++i) { sq += expf(vq[i] - mq); sp += expf(vp[i] - mp); }
    float lseq = mq + logf(sq), lsep = mp + logf(sp);
    float kl = 0.f;
    #pragma unroll
    for (int i = 0; i < NCLS; ++i) {
        float lpq = vq[i] - lseq;
        kl += expf(lpq) * (lpq - (vp[i] - lsep));
    }
    __shared__ float red[256];
    red[threadIdx.x] = kl;
    __syncthreads();
    for (int s = 128; s > 0; s >>= 1) {
        if ((int)threadIdx.x < s) red[threadIdx.x] += red[threadIdx.x + s];
        __syncthreads();
    }
    if (threadIdx.x == 0) atomicAdd(&kl_acc[sidx >> 8], red[0]);
}

// ---------------------------------------------------------------- CE over 512 logits
__global__ void k_ce(const unsigned short* __restrict__ logits,
                     const int* __restrict__ obs_idx, float* __restrict__ ce_acc) {
    int s = (blockIdx.x * 256 + threadIdx.x) >> 6;
    int lane = threadIdx.x & 63;
    union { float4 f4; unsigned short u[8]; } raw;
    raw.f4 = *(const float4*)(logits + (size_t)s * OBS + lane * 8);
    float v[8];
    float m = -1e30f;
    #pragma unroll
    for (int i = 0; i < 8; ++i) { v[i] = bf2f(raw.u[i]); m = fmaxf(m, v[i]); }
    #pragma unroll
    for (int off = 32; off > 0; off >>= 1) m = fmaxf(m, __shfl_xor(m, off));
    float sum = 0.f;
    #pragma unroll
    for (int i = 0; i < 8; ++i) sum += expf(v[i] - m);
    #pragma unroll
    for (int off = 32; off > 0; off >>= 1) sum += __shfl_xor(sum, off);
    float lse = m + logf(sum);
    int tgt = obs_idx[s];
    float tv = 0.f;
    #pragma unroll
    for (int i = 0; i < 8; ++i) if (lane * 8 + i == tgt) tv = v[i];
    #pragma unroll
    for (int off = 32; off > 0; off >>= 1) tv += __shfl_xor(tv, off);
    if (lane == 0) atomicAdd(&ce_acc[s >> 8], lse - tv);
}

// ---------------------------------------------------------------- reward / continue heads
__global__ void k_heads(const unsigned short* __restrict__ dec1,
                        const float* __restrict__ Wr2, const float* __restrict__ br2,
                        const float* __restrict__ Wc2, const float* __restrict__ bc2,
                        const float* __restrict__ rew, const float* __restrict__ done,
                        float* __restrict__ mse_acc, float* __restrict__ bce_acc) {
    int s = (blockIdx.x * 256 + threadIdx.x) >> 6;
    int lane = threadIdx.x & 63;
    float vr = bf2f(dec1[(size_t)s * 192 + 64 + lane]) * Wr2[lane];
    float vc = bf2f(dec1[(size_t)s * 192 + 128 + lane]) * Wc2[lane];
    #pragma unroll
    for (int off = 32; off > 0; off >>= 1) {
        vr += __shfl_xor(vr, off);
        vc += __shfl_xor(vc, off);
    }
    if (lane == 0) {
        float r_pred = vr + br2[0], c_pred = vc + bc2[0];
        float rt = rew[s];
        float sgn = (rt > 0.f) ? 1.f : ((rt < 0.f) ? -1.f : 0.f);
        float r_tgt = sgn * log1pf(fabsf(rt));
        float d = r_pred - r_tgt;
        float ct = 1.f - done[s];
        float bce = fmaxf(c_pred, 0.f) - c_pred * ct + log1pf(expf(-fabsf(c_pred)));
        atomicAdd(&mse_acc[s >> 8], d * d);
        atomicAdd(&bce_acc[s >> 8], bce);
    }
}

// ---------------------------------------------------------------- final reduce
__global__ void k_final(const float* __restrict__ ce_acc, const float* __restrict__ mse_acc,
                        const float* __restrict__ bce_acc, const float* __restrict__ kl_acc,
                        float* __restrict__ out) {
    int t = threadIdx.x;
    float ce = ce_acc[t] * (1.f / 256.f);
    float ms = mse_acc[t] * (1.f / 256.f);
    float bc = bce_acc[t] * (1.f / 256.f);
    float ka = kl_acc[t] * (1.f / 256.f);
    float kt = fmaxf(ka, 1.f);
    #pragma unroll
    for (int off = 32; off > 0; off >>= 1) {
        ce += __shfl_down(ce, off);
        ms += __shfl_down(ms, off);
        bc += __shfl_down(bc, off);
        kt += __shfl_down(kt, off);
    }
    if (t == 0) {
        ce *= (1.f / 64.f); ms *= (1.f / 64.f); bc *= (1.f / 64.f); kt *= (1.f / 64.f);
        out[0] = ce + ms + bc + kt;
        out[1] = ce; out[2] = ms; out[3] = bc; out[4] = kt;
    }
}

// ----------------------------------------------------------------------------------
extern "C" void kernel_launch(void* const* d_in, const int* in_sizes, int n_in,
                              void* d_out, int out_size, void* d_ws, size_t ws_size,
                              hipStream_t stream) {
    const float* obs  = (const float*)d_in[0];
    const float* act  = (const float*)d_in[1];
    const float* rew  = (const float*)d_in[2];
    const float* done = (const float*)d_in[3];
    const float* gum  = (const float*)d_in[4];
    const float* We1  = (const float*)d_in[5];
    const float* be1  = (const float*)d_in[6];
    const float* We2  = (const float*)d_in[7];
    const float* be2  = (const float*)d_in[8];
    const float* Wi   = (const float*)d_in[9];
    const float* Wh   = (const float*)d_in[10];
    const float* bi   = (const float*)d_in[11];
    const float* bh   = (const float*)d_in[12];
    const float* Wp1  = (const float*)d_in[13];
    const float* bp1  = (const float*)d_in[14];
    const float* Wp2  = (const float*)d_in[15];
    const float* bp2  = (const float*)d_in[16];
    const float* Wq1  = (const float*)d_in[17];
    const float* bq1  = (const float*)d_in[18];
    const float* Wq2  = (const float*)d_in[19];
    const float* bq2  = (const float*)d_in[20];
    const float* Wd1  = (const float*)d_in[21];
    const float* bd1  = (const float*)d_in[22];
    const float* Wd2  = (const float*)d_in[23];
    const float* bd2  = (const float*)d_in[24];
    const float* Wr1  = (const float*)d_in[25];
    const float* br1  = (const float*)d_in[26];
    const float* Wr2  = (const float*)d_in[27];
    const float* br2  = (const float*)d_in[28];
    const float* Wc1  = (const float*)d_in[29];
    const float* bc1  = (const float*)d_in[30];
    const float* Wc2  = (const float*)d_in[31];
    const float* bc2  = (const float*)d_in[32];

    char* base = (char*)d_ws;
    size_t off = 0;
    auto alloc = [&](size_t bytes) -> char* {
        char* p = base + off;
        off += (bytes + 255) & ~(size_t)255;
        return p;
    };
    unsigned short* WhT   = (unsigned short*)alloc(3072u * 1024 * 2);
    unsigned short* WizBF = (unsigned short*)alloc(1024u * 3072 * 2);
    unsigned short* Wq1aT = (unsigned short*)alloc(1024u * 1024 * 2);
    unsigned short* Wq1bT = (unsigned short*)alloc(1024u * 512 * 2);
    unsigned short* Wq2T  = (unsigned short*)alloc(1024u * 1024 * 2);
    unsigned short* Wp1T  = (unsigned short*)alloc(1024u * 1024 * 2);
    unsigned short* Wp2T  = (unsigned short*)alloc(1024u * 1024 * 2);
    unsigned short* WdrcT = (unsigned short*)alloc(192u * 2048 * 2);
    unsigned short* Wd2T  = (unsigned short*)alloc(512u * 64 * 2);
    unsigned short* We2T  = (unsigned short*)alloc(512u * 64 * 2);
    float*          b_drc = (float*)alloc(192 * 4);
    unsigned short* XZ    = (unsigned short*)alloc(65u * 256 * 2048 * 2);   // 68 MB
    float*          h_st  = (float*)alloc(256u * 1024 * 4);
    float*          ghbuf = (float*)alloc(256u * 3072 * 4);
    unsigned short* post1cT = (unsigned short*)alloc(65u * SLOTP * 2);      // 34 MB per-step
    int*            zidxT = (int*)alloc(65u * SLOTZ * 4);                   // 2.1 MB per-step
    unsigned short* postL = (unsigned short*)alloc(16384u * 1024 * 2);      // 32 MB (reused: logits)
    unsigned short* Eq    = (unsigned short*)alloc(16384u * 1024 * 2);      // 32 MB (reused: priorL)
    unsigned short* pri1  = (unsigned short*)alloc(16384u * 1024 * 2);      // 32 MB
    unsigned short* dec1  = (unsigned short*)alloc(16384u * 192 * 2);
    float*          acc   = (float*)alloc(256 * 4);
    int*            obs_idx = (int*)alloc(16384 * 4);
    int*            act_idx = (int*)alloc(16384 * 4);
    int*            bar     = (int*)alloc(BAR_INTS * 4);
    unsigned short* embed = pri1;                    // setup-time aliases (pri1 unused then)
    unsigned short* e1    = pri1 + 16384u * 512;

    hipMemsetAsync(h_st, 0, 256u * 1024 * 4, stream);
    hipMemsetAsync(acc, 0, 256 * 4, stream);
    hipMemsetAsync(bar, 0, BAR_INTS * 4, stream);

    k_idx<<<4096, 256, 0, stream>>>(obs, act, obs_idx, act_idx);

    dim3 tb(32, 8);
    k_transp<<<dim3(96, 32), tb, 0, stream>>>(Wh, 3072, WhT, 1024, 0);
    k_cast<<<(1024 * 3072) / 256, 256, 0, stream>>>(Wi, WizBF, 1024 * 3072);
    k_transp<<<dim3(32, 32), tb, 0, stream>>>(Wq1, 1024, Wq1aT, 1024, 0);
    k_transp<<<dim3(32, 16), tb, 0, stream>>>(Wq1 + 1024u * 1024, 1024, Wq1bT, 512, 0);
    k_transp<<<dim3(32, 32), tb, 0, stream>>>(Wq2, 1024, Wq2T, 1024, 0);
    k_transp<<<dim3(32, 32), tb, 0, stream>>>(Wp1, 1024, Wp1T, 1024, 0);
    k_transp<<<dim3(32, 32), tb, 0, stream>>>(Wp2, 1024, Wp2T, 1024, 0);
    k_transp<<<dim3(2, 64),  tb, 0, stream>>>(Wd1, 64, WdrcT, 2048, 0);
    k_transp<<<dim3(2, 64),  tb, 0, stream>>>(Wr1, 64, WdrcT + 64u * 2048, 2048, 0);
    k_transp<<<dim3(2, 64),  tb, 0, stream>>>(Wc1, 64, WdrcT + 128u * 2048, 2048, 0);
    k_transp<<<dim3(16, 2),  tb, 0, stream>>>(Wd2, 512, Wd2T, 64, 0);
    k_transp<<<dim3(16, 2),  tb, 0, stream>>>(We2, 512, We2T, 64, 0);
    k_pack_bias<<<1, 192, 0, stream>>>(bd1, br1, bc1, b_drc);

    // embed & Eq precompute (all 64 steps)
    k_e1<<<4096, 256, 0, stream>>>(obs_idx, We1, be1, e1);
    {
        MJob m = { e1, 64, We2T, be2, nullptr, embed, 512, 512, 64, 2 };
        mfma_gemm<<<dim3(8, 256), 256, 0, stream>>>(m);
    }
    {
        MJob m = { embed, 512, Wq1bT, bq1, nullptr, Eq, 1024, 1024, 512, 2 };
        mfma_gemm<<<dim3(16, 256), 256, 0, stream>>>(m);
    }

    // persistent col-split scan (cooperative launch for co-residency; 2 blocks/CU)
    ScanP SP;
    SP.WhT = WhT; SP.Wq1aT = Wq1aT; SP.Wq2T = Wq2T; SP.WizBF = WizBF; SP.Eq = Eq;
    SP.Wi = Wi; SP.bi = bi; SP.bh = bh; SP.bq2 = bq2; SP.gum = gum;
    SP.act_idx = act_idx;
    SP.XZ = XZ; SP.post1cT = post1cT; SP.postL = postL;
    SP.ghbuf = ghbuf; SP.h_st = h_st; SP.zidxT = zidxT; SP.bar = bar;
    void* kargs[] = { (void*)&SP };
    hipLaunchCooperativeKernel((const void*)k_scan, dim3(NBLK), dim3(256), kargs, 0, stream);

    // deferred batched passes
    unsigned short* Hall = XZ + (size_t)256 * 2048;
    {   // prior1 = elu(H @ Wp1 + bp1)
        MJob m = { Hall, 2048, Wp1T, bp1, nullptr, pri1, 1024, 1024, 1024, 1 | 2 };
        mfma_gemm<<<dim3(16, 256), 256, 0, stream>>>(m);
    }
    {   // priorL = prior1 @ Wp2 + bp2 (into Eq buffer)
        MJob m = { pri1, 1024, Wp2T, bp2, nullptr, Eq, 1024, 1024, 1024, 2 };
        mfma_gemm<<<dim3(16, 256), 256, 0, stream>>>(m);
    }
    k_kl<<<2048, 256, 0, stream>>>(postL, Eq, acc + 192);
    {
        MJob m = { Hall, 2048, WdrcT, b_drc, nullptr, dec1, 192, 192, 2048, 1 | 2 };
        mfma_gemm<<<dim3(3, 256), 256, 0, stream>>>(m);
    }
    {
        MJob m = { dec1, 192, Wd2T, bd2, nullptr, postL, 512, 512, 64, 2 };
        mfma_gemm<<<dim3(8, 256), 256, 0, stream>>>(m);
    }
    k_ce<<<4096, 256, 0, stream>>>(postL, obs_idx, acc + 0);
    k_heads<<<4096, 256, 0, stream>>>(dec1, Wr2, br2, Wc2, bc2, rew, done,
                                      acc + 64, acc + 128);
    k_final<<<1, 64, 0, stream>>>(acc + 0, acc + 64, acc + 128, acc + 192, (float*)d_out);
}